// Round 12
// baseline (164.309 us; speedup 1.0000x reference)
//
#include <hip/hip_runtime.h>
#include <stdint.h>

#define BATCH  2
#define SEQ    2048
#define DMODEL 1024
#define NHEADS 16
#define DKH    64
#define MTOT   (BATCH*SEQ)   // 4096
#define VSTR   (SEQ + 32)    // padded V row stride

typedef unsigned short u16;
typedef __bf16 bf16x8 __attribute__((ext_vector_type(8)));
typedef float  f32x4  __attribute__((ext_vector_type(4)));

extern "C" __device__ float __ocml_native_exp2_f32(float);   // raw v_exp_f32

__device__ __forceinline__ u16 f2bf(float f) {
  union { float f; uint32_t u; } v; v.f = f;
  uint32_t u = v.u;
  return (u16)((u + 0x7FFFu + ((u >> 16) & 1u)) >> 16);   // RNE
}
__device__ __forceinline__ float bf2f(u16 h) {
  union { uint32_t u; float f; } v; v.u = (uint32_t)h << 16; return v.f;
}

__device__ __forceinline__ void gld_lds16(const void* g, void* l) {
  __builtin_amdgcn_global_load_lds(
      (__attribute__((address_space(1))) void*)g,
      (__attribute__((address_space(3))) void*)l, 16, 0, 0);
}

// pack two f32 -> one u32 of 2x bf16 (RNE), gfx950 has no builtin (m240)
__device__ __forceinline__ uint32_t cvtpk(float lo, float hi) {
  uint32_t r;
  asm("v_cvt_pk_bf16_f32 %0, %1, %2" : "=v"(r) : "v"(lo), "v"(hi));
  return r;
}
// gfx950 v_permlane16_swap_b32: odd 16-lane rows of a <-> even rows of b
__device__ __forceinline__ void pl16swap(uint32_t& a, uint32_t& b) {
  asm volatile("v_permlane16_swap_b32 %0, %1" : "+v"(a), "+v"(b));
}

// ---------------- fp32 -> bf16 convert, x + all 4 weights in one launch -----
__global__ void cvt_all(const float* __restrict__ x, const float* __restrict__ wa,
                        const float* __restrict__ wb, const float* __restrict__ wc,
                        const float* __restrict__ wd,
                        u16* __restrict__ xb, u16* __restrict__ wdst) {
  const int blk = blockIdx.x;
  const int tid = threadIdx.x;
  if (blk < 4096) {                    // x: 4M elements
    size_t o = (size_t)blk * 1024 + tid * 4;
    float4 f = *(const float4*)(x + o);
    ushort4 p;
    p.x = f2bf(f.x); p.y = f2bf(f.y); p.z = f2bf(f.z); p.w = f2bf(f.w);
    *(ushort4*)(xb + o) = p;
  } else {                             // weights: 4 x 1M elements, dst contiguous
    int j = blk - 4096;
    const float* ws[4] = {wa, wb, wc, wd};
    size_t src_o = (size_t)(j & 1023) * 1024 + tid * 4;
    size_t dst_o = (size_t)j * 1024 + tid * 4;
    float4 f = *(const float4*)(ws[j >> 10] + src_o);
    ushort4 p;
    p.x = f2bf(f.x); p.y = f2bf(f.y); p.z = f2bf(f.z); p.w = f2bf(f.w);
    *(ushort4*)(wdst + dst_o) = p;
  }
}

// ---------------- fused QKV GEMM: stage A once, 3 B tiles (R10 form) --------
__global__ __launch_bounds__(256, 3) void gemm_qkv(
    const u16* __restrict__ xb, const u16* __restrict__ wq,
    const u16* __restrict__ wk, const u16* __restrict__ wv,
    u16* __restrict__ q, u16* __restrict__ k, u16* __restrict__ v, float qscale) {
  __shared__ __align__(16) u16 lA[128 * 64];
  __shared__ __align__(16) u16 lB[3][64 * 64];

  const int tid  = threadIdx.x;
  const int lane = tid & 63;
  const int lrow = lane & 15;
  const int quad = lane >> 4;
  const int wave = tid >> 6;
  const int wm   = (wave & 1) * 64;
  const int wn   = (wave >> 1) * 32;
  const int sx   = lrow & 7;
  const int m0 = blockIdx.x * 128, n0 = blockIdx.y * 64;
  const u16* Ws[3] = {wq, wk, wv};

  f32x4 acc[3][4][2] = {};

  for (int k0 = 0; k0 < DMODEL; k0 += 64) {
    #pragma unroll
    for (int r = 0; r < 4; ++r) {       // A: 128 rows
      int off  = r * 4096 + tid * 16;
      int row  = off >> 7;
      int c16  = (off >> 4) & 7;
      int colb = (c16 ^ (row & 7)) << 4;
      gld_lds16((const char*)xb + ((size_t)(m0 + row) * DMODEL + k0) * 2 + colb,
                (char*)lA + off);
    }
    #pragma unroll
    for (int z = 0; z < 3; ++z)
      #pragma unroll
      for (int r = 0; r < 2; ++r) {     // B: 64 rows each
        int off  = r * 4096 + tid * 16;
        int row  = off >> 7;
        int c16  = (off >> 4) & 7;
        int colb = (c16 ^ (row & 7)) << 4;
        gld_lds16((const char*)Ws[z] + ((size_t)(n0 + row) * DMODEL + k0) * 2 + colb,
                  (char*)&lB[z][0] + off);
      }
    __syncthreads();
    #pragma unroll
    for (int ks = 0; ks < 2; ++ks) {
      const int ro = ((((ks << 2) | quad) ^ sx) << 3);
      bf16x8 a[4], b[3][2];
      #pragma unroll
      for (int i = 0; i < 4; ++i)
        a[i] = *(const bf16x8*)(lA + (wm + i*16 + lrow) * 64 + ro);
      #pragma unroll
      for (int z = 0; z < 3; ++z)
        #pragma unroll
        for (int j = 0; j < 2; ++j)
          b[z][j] = *(const bf16x8*)(&lB[z][0] + (wn + j*16 + lrow) * 64 + ro);
      #pragma unroll
      for (int z = 0; z < 3; ++z)
        #pragma unroll
        for (int i = 0; i < 4; ++i)
          #pragma unroll
          for (int j = 0; j < 2; ++j)
            acc[z][i][j] = __builtin_amdgcn_mfma_f32_16x16x32_bf16(a[i], b[z][j], acc[z][i][j], 0, 0, 0);
    }
    __syncthreads();
  }

  const int rb = quad * 4, cb = lrow;
  const int h  = blockIdx.y;
  u16* outs[3] = {q, k, v};
  #pragma unroll
  for (int z = 0; z < 3; ++z) {
    u16* out = outs[z];
    if (z == 2) {
      #pragma unroll
      for (int i = 0; i < 4; ++i)
        #pragma unroll
        for (int j = 0; j < 2; ++j) {
          int row0 = m0 + wm + i*16 + rb;
          int d_   = wn + j*16 + cb;
          int b_ = row0 >> 11, s0 = row0 & 2047;
          ushort4 pk;
          pk.x = f2bf(acc[z][i][j][0]); pk.y = f2bf(acc[z][i][j][1]);
          pk.z = f2bf(acc[z][i][j][2]); pk.w = f2bf(acc[z][i][j][3]);
          *(ushort4*)&out[((size_t)(b_*NHEADS + h) * DKH + d_) * VSTR + s0] = pk;
        }
    } else {
      const float scale = (z == 0) ? qscale : 1.0f;
      #pragma unroll
      for (int i = 0; i < 4; ++i)
        #pragma unroll
        for (int j = 0; j < 2; ++j)
          #pragma unroll
          for (int r = 0; r < 4; ++r) {
            int row = m0 + wm + i*16 + rb + r;
            int d_  = wn + j*16 + cb;
            int b_ = row >> 11, s_ = row & 2047;
            out[(((size_t)(b_*NHEADS + h) * SEQ + s_) << 6) + d_] =
                f2bf(acc[z][i][j][r] * scale);
          }
    }
  }
}

// ---------------- output projection: 64x64 tiles, 4 blk/CU supplied ---------
// gemm_out is latency-bound; quadrupling supplied blocks/CU (512->1024 grid,
// 16KB LDS) raises TLP (the R1->R2 proven lever). B-traffic x2 but wo=2MB is
// L2-resident. 2x2 waves of 32x32; VGPR ~70 << 128 cap, no spill risk.
__global__ __launch_bounds__(256, 4) void gemm_out(
    const u16* __restrict__ ab, const u16* __restrict__ wo, float* __restrict__ out) {
  __shared__ __align__(16) u16 lA[64 * 64];
  __shared__ __align__(16) u16 lB[64 * 64];
  const int m0 = blockIdx.x * 64, n0 = blockIdx.y * 64;

  const int tid  = threadIdx.x;
  const int lane = tid & 63;
  const int lrow = lane & 15;
  const int quad = lane >> 4;
  const int wave = tid >> 6;
  const int wm   = (wave & 1) * 32;
  const int wn   = (wave >> 1) * 32;
  const int sx   = lrow & 7;

  f32x4 acc[2][2] = {};

  for (int k0 = 0; k0 < DMODEL; k0 += 64) {
    #pragma unroll
    for (int r = 0; r < 2; ++r) {
      int off  = r * 4096 + tid * 16;
      int row  = off >> 7;
      int colb = ((((off >> 4) & 7) ^ (row & 7))) << 4;
      gld_lds16((const char*)ab + ((size_t)(m0 + row) * DMODEL + k0) * 2 + colb,
                (char*)lA + off);
    }
    #pragma unroll
    for (int r = 0; r < 2; ++r) {
      int off  = r * 4096 + tid * 16;
      int row  = off >> 7;
      int colb = ((((off >> 4) & 7) ^ (row & 7))) << 4;
      gld_lds16((const char*)wo + ((size_t)(n0 + row) * DMODEL + k0) * 2 + colb,
                (char*)lB + off);
    }
    __syncthreads();
    #pragma unroll
    for (int ks = 0; ks < 2; ++ks) {
      bf16x8 a[2], b[2];
      const int ro = ((((ks << 2) | quad) ^ sx) << 3);
      #pragma unroll
      for (int i = 0; i < 2; ++i)
        a[i] = *(const bf16x8*)(lA + (wm + i*16 + lrow) * 64 + ro);
      #pragma unroll
      for (int j = 0; j < 2; ++j)
        b[j] = *(const bf16x8*)(lB + (wn + j*16 + lrow) * 64 + ro);
      #pragma unroll
      for (int i = 0; i < 2; ++i)
        #pragma unroll
        for (int j = 0; j < 2; ++j)
          acc[i][j] = __builtin_amdgcn_mfma_f32_16x16x32_bf16(a[i], b[j], acc[i][j], 0, 0, 0);
    }
    __syncthreads();
  }

  const int rb = quad * 4, cb = lrow;
  #pragma unroll
  for (int i = 0; i < 2; ++i)
    #pragma unroll
    for (int j = 0; j < 2; ++j)
      #pragma unroll
      for (int r = 0; r < 4; ++r)
        out[(size_t)(m0 + wm + i*16 + rb + r) * DMODEL + (n0 + wn + j*16 + cb)]
            = acc[i][j][r];
}

// ---------------- flash attention v15: v12 (3 blk/CU) + masked-tile skip ----
// job entry e = u*4 + c; LPT: 28 len-8, then len-6, len-4, len-2 (4 each)
__device__ const uint8_t JT[40] = {
  60,61,62,63, 56,57,58, 52,53,54, 48,49,50, 44,45,46, 40,41, 36,37,
  32,33, 28,29, 24, 20, 16, 12,
  59,42,25,8, 55,38,21,4, 51,34,17,0
};

__device__ __forceinline__ void stage_kv(const u16* Kg, const u16* Vg, int t,
                                         u16* lK, u16* lV, int tid) {
  #pragma unroll
  for (int r = 0; r < 2; ++r) {
    int off  = r * 4096 + tid * 16;
    int row  = off >> 7;
    int colb = (((off >> 4) & 7) ^ (row & 7)) << 4;
    gld_lds16((const char*)Kg + ((size_t)(t*64 + row) * DKH) * 2 + colb,
              (char*)lK + off);
    gld_lds16((const char*)Vg + ((size_t)row * VSTR + t*64) * 2 + colb,
              (char*)lV + off);
  }
}

__global__ __launch_bounds__(256, 3) void attn(
    const u16* __restrict__ Q, const u16* __restrict__ K,
    const u16* __restrict__ V, u16* __restrict__ O,
    u16* __restrict__ po, float* __restrict__ pl) {
  __shared__ __align__(16) u16 lK[2][64 * 64];
  __shared__ __align__(16) u16 lV[2][64 * 64];

  const int tid  = threadIdx.x;
  const int wid  = tid >> 6;          // wave owns 32 q-rows: 32*wid..+31
  const int lane = tid & 63;
  const int lrow = lane & 15;
  const int quad = lane >> 4;
  const int sx   = lrow & 7;
  const int pq   = ((quad & 1) << 1) | (quad >> 1);   // pi(quad) for V frags

  const int g  = blockIdx.x >> 5;
  const int bh = blockIdx.x & 31;
  const int e  = JT[g];
  const int u  = e >> 2, c = e & 3;
  const int lo = c * 8;
  const int T  = 2*u + 2;
  const int hi = (lo + 8 < T) ? lo + 8 : T;
  const int td = 2*u + (wid >> 1);    // this wave's diagonal tile
  const int qg0 = 128*u + 32*wid;     // wave's first global q row

  const u16* Qg = Q + (size_t)bh * SEQ * DKH;
  const u16* Kg = K + (size_t)bh * SEQ * DKH;
  const u16* Vg = V + (size_t)bh * DKH * VSTR;

  bf16x8 aq[2][2];
  #pragma unroll
  for (int i = 0; i < 2; ++i)
    #pragma unroll
    for (int ks = 0; ks < 2; ++ks)
      aq[i][ks] = *(const bf16x8*)(Qg + (size_t)(qg0 + 16*i + lrow) * DKH + ks*32 + quad*8);

  f32x4 o_acc[2][4] = {};
  float l_acc[2] = {};

  stage_kv(Kg, Vg, lo, &lK[0][0], &lV[0][0], tid);
  __syncthreads();
  int cur = 0;

  for (int t = lo; t < hi; ++t) {
    if (t + 1 < hi)
      stage_kv(Kg, Vg, t + 1, &lK[cur ^ 1][0], &lV[cur ^ 1][0], tid);

    if (t <= td) {                     // wave-uniform: skip fully-masked tiles
      // ---- K fragments, then QK^T for both i-subtiles ---------------------
      f32x4 s_acc[2][4] = {};
      {
        bf16x8 kf[2][4];
        #pragma unroll
        for (int ks = 0; ks < 2; ++ks) {
          const int kro = ((((ks << 2) | quad) ^ sx) << 3);
          #pragma unroll
          for (int j = 0; j < 4; ++j)
            kf[ks][j] = *(const bf16x8*)(&lK[cur][0] + (j*16 + lrow) * 64 + kro);
        }
        __builtin_amdgcn_s_setprio(1);
        #pragma unroll
        for (int i = 0; i < 2; ++i)
          #pragma unroll
          for (int ks = 0; ks < 2; ++ks)
            #pragma unroll
            for (int j = 0; j < 4; ++j)
              s_acc[i][j] = __builtin_amdgcn_mfma_f32_16x16x32_bf16(kf[ks][j], aq[i][ks], s_acc[i][j], 0, 0, 0);
        __builtin_amdgcn_s_setprio(0);
      }

      // ---- V fragments (kf dead; ds_read latency hides under softmax) -----
      bf16x8 vf[2][4];
      #pragma unroll
      for (int ks = 0; ks < 2; ++ks) {
        const int vro = ((((ks << 2) | pq) ^ sx) << 3);
        #pragma unroll
        for (int j = 0; j < 4; ++j)
          vf[ks][j] = *(const bf16x8*)(&lV[cur][0] + (j*16 + lrow) * 64 + vro);
      }

      #pragma unroll
      for (int i = 0; i < 2; ++i) {
        if (t >= td) {
          const int qrel = qg0 + 16*i + lrow - 64*t;
          #pragma unroll
          for (int j = 0; j < 4; ++j) {
            int kl = j*16 + quad*4;
            #pragma unroll
            for (int r = 0; r < 4; ++r)
              if (kl + r > qrel) s_acc[i][j][r] = -1e30f;
          }
        }

        // exp2 + per-lane row-sum + pack to bf16 pairs
        uint32_t w[4][2];
        float ls = 0.f;
        #pragma unroll
        for (int j = 0; j < 4; ++j) {
          float p0 = __ocml_native_exp2_f32(s_acc[i][j][0]);
          float p1 = __ocml_native_exp2_f32(s_acc[i][j][1]);
          float p2 = __ocml_native_exp2_f32(s_acc[i][j][2]);
          float p3 = __ocml_native_exp2_f32(s_acc[i][j][3]);
          ls += (p0 + p1) + (p2 + p3);
          w[j][0] = cvtpk(p0, p1);
          w[j][1] = cvtpk(p2, p3);
        }
        l_acc[i] += ls;

        // redistribute across quads: (A0,A1)->ks0 frag, (A2,A3)->ks1 frag
        pl16swap(w[0][0], w[1][0]);
        pl16swap(w[0][1], w[1][1]);
        pl16swap(w[2][0], w[3][0]);
        pl16swap(w[2][1], w[3][1]);
        union { uint32_t u[4]; bf16x8 v; } g0, g1;
        g0.u[0] = w[0][0]; g0.u[1] = w[0][1]; g0.u[2] = w[1][0]; g0.u[3] = w[1][1];
        g1.u[0] = w[2][0]; g1.u[1] = w[2][1]; g1.u[2] = w[3][0]; g1.u[3] = w[3][1];

        __builtin_amdgcn_s_setprio(1);
        #pragma unroll
        for (int j = 0; j < 4; ++j)
          o_acc[i][j] = __builtin_amdgcn_mfma_f32_16x16x32_bf16(g0.v, vf[0][j], o_acc[i][j], 0, 0, 0);
        #pragma unroll
        for (int j = 0; j < 4; ++j)
          o_acc[i][j] = __builtin_amdgcn_mfma_f32_16x16x32_bf16(g1.v, vf[1][j], o_acc[i][j], 0, 0, 0);
        __builtin_amdgcn_s_setprio(0);
      }
    }

    __syncthreads();          // drains prefetch (overlapped with compute above)
    cur ^= 1;
  }

  // l: reduce across quads (k-parallel), then broadcast per output row
  float lr[2][4];
  #pragma unroll
  for (int i = 0; i < 2; ++i) {
    float s = l_acc[i];
    s += __shfl_xor(s, 16, 64);
    s += __shfl_xor(s, 32, 64);
    #pragma unroll
    for (int r = 0; r < 4; ++r)
      lr[i][r] = __shfl(s, quad*4 + r, 16);
  }

  if (T <= 8) {                        // single chunk: write final output
    const int h = bh & 15, b_ = bh >> 4;
    #pragma unroll
    for (int i = 0; i < 2; ++i)
      #pragma unroll
      for (int j = 0; j < 4; ++j)
        #pragma unroll
        for (int r = 0; r < 4; ++r) {
          int sg = qg0 + 16*i + quad*4 + r;
          O[(size_t)(b_ * SEQ + sg) * DMODEL + h * DKH + j*16 + lrow]
              = f2bf(o_acc[i][j][r] / lr[i][r]);
        }
  } else {                             // partial: old 64-row strip slots
    const int pold = td;               // 2u + (wid>>1), in 8..31
    const int base = (pold < 16) ? (pold - 8) * 2
                   : (pold < 24) ? 16 + (pold - 16) * 3
                   :               40 + (pold - 24) * 4;
    const int slot = (base + c) * 32 + bh;
    const int r64  = 32 * (wid & 1);   // row offset inside the 64-row strip
    #pragma unroll
    for (int i = 0; i < 2; ++i) {
      #pragma unroll
      for (int j = 0; j < 4; ++j) {
        ushort4 pk;
        pk.x = f2bf(o_acc[i][j][0]); pk.y = f2bf(o_acc[i][j][1]);
        pk.z = f2bf(o_acc[i][j][2]); pk.w = f2bf(o_acc[i][j][3]);
        *(ushort4*)&po[(size_t)slot * 4096 + (j*16 + lrow) * 64 + r64 + 16*i + quad*4] = pk;
      }
      if (lrow == 0)
        #pragma unroll
        for (int r = 0; r < 4; ++r)
          pl[slot * 64 + r64 + 16*i + quad*4 + r] = lr[i][r];
    }
  }
}

// ---------------- combine chunk-partials for strips p>=8 --------------------
__global__ __launch_bounds__(256) void combine(
    const u16* __restrict__ po, const float* __restrict__ pl, u16* __restrict__ ab) {
  __shared__ u16 Ls[64][68];
  const int b  = blockIdx.x;          // 0..767
  const int p  = 8 + (b >> 5);
  const int bh = b & 31;
  const int t  = threadIdx.x;
  const int col = t >> 2;             // 0..63
  const int r0  = (t & 3) * 16;       // 16-row slab
  const int base = (p < 16) ? (p - 8) * 2
                 : (p < 24) ? 16 + (p - 16) * 3
                 :            40 + (p - 24) * 4;
  const int nc   = (p < 16) ? 2 : (p < 24) ? 3 : 4;

  float acc[16], lsum[16];
  const size_t s0 = (size_t)(base * 32 + bh);
  const u16*   q0 = po + s0 * 4096 + col * 64 + r0;
  const float* l0 = pl + s0 * 64 + r0;
  #pragma unroll
  for (int q4 = 0; q4 < 4; ++q4) {
    ushort4 a  = *(const ushort4*)(q0 + q4 * 4);
    ushort4 c2 = *(const ushort4*)(q0 + (size_t)32 * 4096 + q4 * 4);
    acc[q4*4+0] = bf2f(a.x) + bf2f(c2.x);
    acc[q4*4+1] = bf2f(a.y) + bf2f(c2.y);
    acc[q4*4+2] = bf2f(a.z) + bf2f(c2.z);
    acc[q4*4+3] = bf2f(a.w) + bf2f(c2.w);
    float4 f = *(const float4*)(l0 + q4 * 4);
    float4 g = *(const float4*)(l0 + 32 * 64 + q4 * 4);
    lsum[q4*4+0] = f.x + g.x; lsum[q4*4+1] = f.y + g.y;
    lsum[q4*4+2] = f.z + g.z; lsum[q4*4+3] = f.w + g.w;
  }
  if (nc >= 3) {
    #pragma unroll
    for (int q4 = 0; q4 < 4; ++q4) {
      ushort4 a = *(const ushort4*)(q0 + (size_t)64 * 4096 + q4 * 4);
      acc[q4*4+0] += bf2f(a.x); acc[q4*4+1] += bf2f(a.y);
      acc[q4*4+2] += bf2f(a.z); acc[q4*4+3] += bf2f(a.w);
      float4 f = *(const float4*)(l0 + 64 * 64 + q4 * 4);
      lsum[q4*4+0] += f.x; lsum[q4*4+1] += f.y;
      lsum[q4*4+2] += f.z; lsum[q4*4+3] += f.w;
    }
  }
  if (nc == 4) {
    #pragma unroll
    for (int q4 = 0; q4 < 4; ++q4) {
      ushort4 a = *(const ushort4*)(q0 + (size_t)96 * 4096 + q4 * 4);
      acc[q4*4+0] += bf2f(a.x); acc[q4*4+1] += bf2f(a.y);
      acc[q4*4+2] += bf2f(a.z); acc[q4*4+3] += bf2f(a.w);
      float4 f = *(const float4*)(l0 + 96 * 64 + q4 * 4);
      lsum[q4*4+0] += f.x; lsum[q4*4+1] += f.y;
      lsum[q4*4+2] += f.z; lsum[q4*4+3] += f.w;
    }
  }
  #pragma unroll
  for (int q = 0; q < 16; ++q)
    Ls[r0 + q][col] = f2bf(acc[q] / lsum[q]);
  __syncthreads();

  const int row = t >> 2;
  const int c0  = (t & 3) * 16;
  const int b_ = bh >> 4, h = bh & 15;
  u16* dst = ab + (size_t)(b_ * SEQ + 64 * p + row) * DMODEL + h * DKH + c0;
  #pragma unroll
  for (int q = 0; q < 16; q += 4)
    *(ushort4*)(dst + q) = *(const ushort4*)&Ls[row][c0 + q];
}

// ---------------- launcher ---------------------------------------------------
extern "C" void kernel_launch(void* const* d_in, const int* in_sizes, int n_in,
                              void* d_out, int out_size, void* d_ws, size_t ws_size,
                              hipStream_t stream) {
  const float* x  = (const float*)d_in[0];
  const float* Wq = (const float*)d_in[1];
  const float* Wk = (const float*)d_in[2];
  const float* Wv = (const float*)d_in[3];
  const float* Wo = (const float*)d_in[4];
  float* out = (float*)d_out;

  u16* xb  = (u16*)d_ws;                               // 4M u16
  u16* wqb = xb  + (size_t)MTOT * DMODEL;              // 1M each
  u16* wkb = wqb + (size_t)DMODEL * DMODEL;
  u16* wvb = wkb + (size_t)DMODEL * DMODEL;
  u16* wob = wvb + (size_t)DMODEL * DMODEL;
  u16* qb  = wob + (size_t)DMODEL * DMODEL;            // [B,H,S,dk]
  u16* kb  = qb  + (size_t)MTOT * DMODEL;              // [B,H,S,dk]
  u16* vb  = kb  + (size_t)MTOT * DMODEL;              // [B,H,dk,VSTR]
  u16* ab  = vb  + (size_t)BATCH * NHEADS * DKH * VSTR;
  u16* po  = ab  + (size_t)MTOT * DMODEL;              // 2304 slots x 4096 u16
  float* pl = (float*)(po + (size_t)2304 * 4096);      // 2304 x 64 f32

  cvt_all<<<8192, 256, 0, stream>>>(x, Wq, Wk, Wv, Wo, xb, wqb);

  const float qscale = 0.125f * 1.44269504088896340736f;
  gemm_qkv<<<dim3(32, 16), 256, 0, stream>>>(
      xb, wqb, wkb, wvb, qb, kb, vb, qscale);

  attn<<<1280, 256, 0, stream>>>(qb, kb, vb, ab, po, pl);
  combine<<<768, 256, 0, stream>>>(po, pl, ab);

  gemm_out<<<dim3(64, 16), 256, 0, stream>>>(ab, wob, out);
}

// Round 13
// 162.665 us; speedup vs baseline: 1.0101x; 1.0101x over previous
//
#include <hip/hip_runtime.h>
#include <stdint.h>

#define BATCH  2
#define SEQ    2048
#define DMODEL 1024
#define NHEADS 16
#define DKH    64
#define MTOT   (BATCH*SEQ)   // 4096
#define VSTR   (SEQ + 32)    // padded V row stride

typedef unsigned short u16;
typedef __bf16 bf16x8 __attribute__((ext_vector_type(8)));
typedef float  f32x4  __attribute__((ext_vector_type(4)));

extern "C" __device__ float __ocml_native_exp2_f32(float);   // raw v_exp_f32

__device__ __forceinline__ u16 f2bf(float f) {
  union { float f; uint32_t u; } v; v.f = f;
  uint32_t u = v.u;
  return (u16)((u + 0x7FFFu + ((u >> 16) & 1u)) >> 16);   // RNE
}
__device__ __forceinline__ float bf2f(u16 h) {
  union { uint32_t u; float f; } v; v.u = (uint32_t)h << 16; return v.f;
}

__device__ __forceinline__ void gld_lds16(const void* g, void* l) {
  __builtin_amdgcn_global_load_lds(
      (__attribute__((address_space(1))) void*)g,
      (__attribute__((address_space(3))) void*)l, 16, 0, 0);
}

// pack two f32 -> one u32 of 2x bf16 (RNE), gfx950 has no builtin (m240)
__device__ __forceinline__ uint32_t cvtpk(float lo, float hi) {
  uint32_t r;
  asm("v_cvt_pk_bf16_f32 %0, %1, %2" : "=v"(r) : "v"(lo), "v"(hi));
  return r;
}
// gfx950 v_permlane16_swap_b32: odd 16-lane rows of a <-> even rows of b
__device__ __forceinline__ void pl16swap(uint32_t& a, uint32_t& b) {
  asm volatile("v_permlane16_swap_b32 %0, %1" : "+v"(a), "+v"(b));
}

// ---------------- fp32 -> bf16 convert, x + all 4 weights in one launch -----
__global__ void cvt_all(const float* __restrict__ x, const float* __restrict__ wa,
                        const float* __restrict__ wb, const float* __restrict__ wc,
                        const float* __restrict__ wd,
                        u16* __restrict__ xb, u16* __restrict__ wdst) {
  const int blk = blockIdx.x;
  const int tid = threadIdx.x;
  if (blk < 4096) {                    // x: 4M elements
    size_t o = (size_t)blk * 1024 + tid * 4;
    float4 f = *(const float4*)(x + o);
    ushort4 p;
    p.x = f2bf(f.x); p.y = f2bf(f.y); p.z = f2bf(f.z); p.w = f2bf(f.w);
    *(ushort4*)(xb + o) = p;
  } else {                             // weights: 4 x 1M elements, dst contiguous
    int j = blk - 4096;
    const float* ws[4] = {wa, wb, wc, wd};
    size_t src_o = (size_t)(j & 1023) * 1024 + tid * 4;
    size_t dst_o = (size_t)j * 1024 + tid * 4;
    float4 f = *(const float4*)(ws[j >> 10] + src_o);
    ushort4 p;
    p.x = f2bf(f.x); p.y = f2bf(f.y); p.z = f2bf(f.z); p.w = f2bf(f.w);
    *(ushort4*)(wdst + dst_o) = p;
  }
}

// ---------------- fused QKV GEMM: stage A once, 3 B tiles + XCD n-pinning ---
// T1: pin 2 n-indices per XCD (bijective remap of the 512-block grid) so each
// XCD's weight working set is 768KB (L2-resident) instead of all 6MB
// thrashing 8 L2s. m-order preserved within an XCD.
__global__ __launch_bounds__(256, 3) void gemm_qkv(
    const u16* __restrict__ xb, const u16* __restrict__ wq,
    const u16* __restrict__ wk, const u16* __restrict__ wv,
    u16* __restrict__ q, u16* __restrict__ k, u16* __restrict__ v, float qscale) {
  __shared__ __align__(16) u16 lA[128 * 64];
  __shared__ __align__(16) u16 lB[3][64 * 64];

  const int tid  = threadIdx.x;
  const int lane = tid & 63;
  const int lrow = lane & 15;
  const int quad = lane >> 4;
  const int wave = tid >> 6;
  const int wm   = (wave & 1) * 64;
  const int wn   = (wave >> 1) * 32;
  const int sx   = lrow & 7;

  // XCD-aware remap: bid = by*32+bx (dispatch order); xcd=bid&7 gets n-pair
  const int bid   = blockIdx.y * 32 + blockIdx.x;
  const int xcd   = bid & 7;
  const int slot  = bid >> 3;            // 0..63
  const int m0    = (slot >> 1) * 128;
  const int n_idx = xcd * 2 + (slot & 1);
  const int n0    = n_idx * 64;
  const u16* Ws[3] = {wq, wk, wv};

  f32x4 acc[3][4][2] = {};

  for (int k0 = 0; k0 < DMODEL; k0 += 64) {
    #pragma unroll
    for (int r = 0; r < 4; ++r) {       // A: 128 rows
      int off  = r * 4096 + tid * 16;
      int row  = off >> 7;
      int c16  = (off >> 4) & 7;
      int colb = (c16 ^ (row & 7)) << 4;
      gld_lds16((const char*)xb + ((size_t)(m0 + row) * DMODEL + k0) * 2 + colb,
                (char*)lA + off);
    }
    #pragma unroll
    for (int z = 0; z < 3; ++z)
      #pragma unroll
      for (int r = 0; r < 2; ++r) {     // B: 64 rows each
        int off  = r * 4096 + tid * 16;
        int row  = off >> 7;
        int c16  = (off >> 4) & 7;
        int colb = (c16 ^ (row & 7)) << 4;
        gld_lds16((const char*)Ws[z] + ((size_t)(n0 + row) * DMODEL + k0) * 2 + colb,
                  (char*)&lB[z][0] + off);
      }
    __syncthreads();
    #pragma unroll
    for (int ks = 0; ks < 2; ++ks) {
      const int ro = ((((ks << 2) | quad) ^ sx) << 3);
      bf16x8 a[4], b[3][2];
      #pragma unroll
      for (int i = 0; i < 4; ++i)
        a[i] = *(const bf16x8*)(lA + (wm + i*16 + lrow) * 64 + ro);
      #pragma unroll
      for (int z = 0; z < 3; ++z)
        #pragma unroll
        for (int j = 0; j < 2; ++j)
          b[z][j] = *(const bf16x8*)(&lB[z][0] + (wn + j*16 + lrow) * 64 + ro);
      #pragma unroll
      for (int z = 0; z < 3; ++z)
        #pragma unroll
        for (int i = 0; i < 4; ++i)
          #pragma unroll
          for (int j = 0; j < 2; ++j)
            acc[z][i][j] = __builtin_amdgcn_mfma_f32_16x16x32_bf16(a[i], b[z][j], acc[z][i][j], 0, 0, 0);
    }
    __syncthreads();
  }

  const int rb = quad * 4, cb = lrow;
  const int h  = n_idx;
  u16* outs[3] = {q, k, v};
  #pragma unroll
  for (int z = 0; z < 3; ++z) {
    u16* out = outs[z];
    if (z == 2) {
      #pragma unroll
      for (int i = 0; i < 4; ++i)
        #pragma unroll
        for (int j = 0; j < 2; ++j) {
          int row0 = m0 + wm + i*16 + rb;
          int d_   = wn + j*16 + cb;
          int b_ = row0 >> 11, s0 = row0 & 2047;
          ushort4 pk;
          pk.x = f2bf(acc[z][i][j][0]); pk.y = f2bf(acc[z][i][j][1]);
          pk.z = f2bf(acc[z][i][j][2]); pk.w = f2bf(acc[z][i][j][3]);
          *(ushort4*)&out[((size_t)(b_*NHEADS + h) * DKH + d_) * VSTR + s0] = pk;
        }
    } else {
      const float scale = (z == 0) ? qscale : 1.0f;
      #pragma unroll
      for (int i = 0; i < 4; ++i)
        #pragma unroll
        for (int j = 0; j < 2; ++j)
          #pragma unroll
          for (int r = 0; r < 4; ++r) {
            int row = m0 + wm + i*16 + rb + r;
            int d_  = wn + j*16 + cb;
            int b_ = row >> 11, s_ = row & 2047;
            out[(((size_t)(b_*NHEADS + h) * SEQ + s_) << 6) + d_] =
                f2bf(acc[z][i][j][r] * scale);
          }
    }
  }
}

// ---------------- GEMM core: 128x64 block tile (for gemm_out, R10 form) -----
__device__ __forceinline__ void gemm_core64(const u16* A, const u16* W,
                                            int m0, int n0, f32x4 acc[4][2],
                                            u16* lA, u16* lB) {
  const int tid  = threadIdx.x;
  const int lane = tid & 63;
  const int lrow = lane & 15;
  const int quad = lane >> 4;
  const int wave = tid >> 6;
  const int wm   = (wave & 1) * 64;
  const int wn   = (wave >> 1) * 32;
  const int sx   = lrow & 7;

  for (int k0 = 0; k0 < DMODEL; k0 += 64) {
    #pragma unroll
    for (int r = 0; r < 4; ++r) {
      int off  = r * 4096 + tid * 16;
      int row  = off >> 7;
      int c16  = (off >> 4) & 7;
      int colb = (c16 ^ (row & 7)) << 4;
      gld_lds16((const char*)A + ((size_t)(m0 + row) * DMODEL + k0) * 2 + colb,
                (char*)lA + off);
    }
    #pragma unroll
    for (int r = 0; r < 2; ++r) {
      int off  = r * 4096 + tid * 16;
      int row  = off >> 7;
      int c16  = (off >> 4) & 7;
      int colb = (c16 ^ (row & 7)) << 4;
      gld_lds16((const char*)W + ((size_t)(n0 + row) * DMODEL + k0) * 2 + colb,
                (char*)lB + off);
    }
    __syncthreads();
    #pragma unroll
    for (int ks = 0; ks < 2; ++ks) {
      bf16x8 a[4], b[2];
      const int ro = ((((ks << 2) | quad) ^ sx) << 3);
      #pragma unroll
      for (int i = 0; i < 4; ++i)
        a[i] = *(const bf16x8*)(lA + (wm + i*16 + lrow) * 64 + ro);
      #pragma unroll
      for (int j = 0; j < 2; ++j)
        b[j] = *(const bf16x8*)(lB + (wn + j*16 + lrow) * 64 + ro);
      #pragma unroll
      for (int i = 0; i < 4; ++i)
        #pragma unroll
        for (int j = 0; j < 2; ++j)
          acc[i][j] = __builtin_amdgcn_mfma_f32_16x16x32_bf16(a[i], b[j], acc[i][j], 0, 0, 0);
    }
    __syncthreads();
  }
}

// ---------------- output projection -> fp32 (R10 form) ----------------------
__global__ __launch_bounds__(256, 3) void gemm_out(
    const u16* __restrict__ ab, const u16* __restrict__ wo, float* __restrict__ out) {
  __shared__ __align__(16) u16 lA[128 * 64];
  __shared__ __align__(16) u16 lB[64 * 64];
  const int m0 = blockIdx.x * 128, n0 = blockIdx.y * 64;
  f32x4 acc[4][2] = {};
  gemm_core64(ab, wo, m0, n0, acc, lA, lB);

  const int lane = threadIdx.x & 63;
  const int wave = threadIdx.x >> 6;
  const int wm = (wave & 1) * 64, wn = (wave >> 1) * 32;
  const int rb = (lane >> 4) * 4, cb = lane & 15;
  #pragma unroll
  for (int i = 0; i < 4; ++i)
    #pragma unroll
    for (int j = 0; j < 2; ++j)
      #pragma unroll
      for (int r = 0; r < 4; ++r)
        out[(size_t)(m0 + wm + i*16 + rb + r) * DMODEL + (n0 + wn + j*16 + cb)]
            = acc[i][j][r];
}

// ---------------- flash attention v16: v15 + XCD bh-pinning -----------------
// T1: bijective bid remap pins bh = xcd (mod 8), so each XCD's L2 holds the
// K/V of its 4 bh's (2MB <= 4MB L2); the 40 jobs/bh re-read K/V from L2
// instead of L3 -> lower exposed latency at the prefetch drain. LPT order
// preserved (g monotone in bid).
// job entry e = u*4 + c; LPT: 28 len-8, then len-6, len-4, len-2 (4 each)
__device__ const uint8_t JT[40] = {
  60,61,62,63, 56,57,58, 52,53,54, 48,49,50, 44,45,46, 40,41, 36,37,
  32,33, 28,29, 24, 20, 16, 12,
  59,42,25,8, 55,38,21,4, 51,34,17,0
};

__device__ __forceinline__ void stage_kv(const u16* Kg, const u16* Vg, int t,
                                         u16* lK, u16* lV, int tid) {
  #pragma unroll
  for (int r = 0; r < 2; ++r) {
    int off  = r * 4096 + tid * 16;
    int row  = off >> 7;
    int colb = (((off >> 4) & 7) ^ (row & 7)) << 4;
    gld_lds16((const char*)Kg + ((size_t)(t*64 + row) * DKH) * 2 + colb,
              (char*)lK + off);
    gld_lds16((const char*)Vg + ((size_t)row * VSTR + t*64) * 2 + colb,
              (char*)lV + off);
  }
}

__global__ __launch_bounds__(256, 3) void attn(
    const u16* __restrict__ Q, const u16* __restrict__ K,
    const u16* __restrict__ V, u16* __restrict__ O,
    u16* __restrict__ po, float* __restrict__ pl) {
  __shared__ __align__(16) u16 lK[2][64 * 64];
  __shared__ __align__(16) u16 lV[2][64 * 64];

  const int tid  = threadIdx.x;
  const int wid  = tid >> 6;          // wave owns 32 q-rows: 32*wid..+31
  const int lane = tid & 63;
  const int lrow = lane & 15;
  const int quad = lane >> 4;
  const int sx   = lrow & 7;
  const int pq   = ((quad & 1) << 1) | (quad >> 1);   // pi(quad) for V frags

  // XCD-aware remap: xcd = bid&7 owns bh in {xcd, xcd+8, xcd+16, xcd+24}
  const int bid  = blockIdx.x;
  const int xcd  = bid & 7;
  const int slot = bid >> 3;          // 0..159
  const int bh   = ((slot & 3) << 3) | xcd;
  const int g    = slot >> 2;         // 0..39, monotone in bid -> LPT kept
  const int e  = JT[g];
  const int u  = e >> 2, c = e & 3;
  const int lo = c * 8;
  const int T  = 2*u + 2;
  const int hi = (lo + 8 < T) ? lo + 8 : T;
  const int td = 2*u + (wid >> 1);    // this wave's diagonal tile
  const int qg0 = 128*u + 32*wid;     // wave's first global q row

  const u16* Qg = Q + (size_t)bh * SEQ * DKH;
  const u16* Kg = K + (size_t)bh * SEQ * DKH;
  const u16* Vg = V + (size_t)bh * DKH * VSTR;

  bf16x8 aq[2][2];
  #pragma unroll
  for (int i = 0; i < 2; ++i)
    #pragma unroll
    for (int ks = 0; ks < 2; ++ks)
      aq[i][ks] = *(const bf16x8*)(Qg + (size_t)(qg0 + 16*i + lrow) * DKH + ks*32 + quad*8);

  f32x4 o_acc[2][4] = {};
  float l_acc[2] = {};

  stage_kv(Kg, Vg, lo, &lK[0][0], &lV[0][0], tid);
  __syncthreads();
  int cur = 0;

  for (int t = lo; t < hi; ++t) {
    if (t + 1 < hi)
      stage_kv(Kg, Vg, t + 1, &lK[cur ^ 1][0], &lV[cur ^ 1][0], tid);

    if (t <= td) {                     // wave-uniform: skip fully-masked tiles
      // ---- K fragments, then QK^T for both i-subtiles ---------------------
      f32x4 s_acc[2][4] = {};
      {
        bf16x8 kf[2][4];
        #pragma unroll
        for (int ks = 0; ks < 2; ++ks) {
          const int kro = ((((ks << 2) | quad) ^ sx) << 3);
          #pragma unroll
          for (int j = 0; j < 4; ++j)
            kf[ks][j] = *(const bf16x8*)(&lK[cur][0] + (j*16 + lrow) * 64 + kro);
        }
        __builtin_amdgcn_s_setprio(1);
        #pragma unroll
        for (int i = 0; i < 2; ++i)
          #pragma unroll
          for (int ks = 0; ks < 2; ++ks)
            #pragma unroll
            for (int j = 0; j < 4; ++j)
              s_acc[i][j] = __builtin_amdgcn_mfma_f32_16x16x32_bf16(kf[ks][j], aq[i][ks], s_acc[i][j], 0, 0, 0);
        __builtin_amdgcn_s_setprio(0);
      }

      // ---- V fragments (kf dead; ds_read latency hides under softmax) -----
      bf16x8 vf[2][4];
      #pragma unroll
      for (int ks = 0; ks < 2; ++ks) {
        const int vro = ((((ks << 2) | pq) ^ sx) << 3);
        #pragma unroll
        for (int j = 0; j < 4; ++j)
          vf[ks][j] = *(const bf16x8*)(&lV[cur][0] + (j*16 + lrow) * 64 + vro);
      }

      #pragma unroll
      for (int i = 0; i < 2; ++i) {
        if (t >= td) {
          const int qrel = qg0 + 16*i + lrow - 64*t;
          #pragma unroll
          for (int j = 0; j < 4; ++j) {
            int kl = j*16 + quad*4;
            #pragma unroll
            for (int r = 0; r < 4; ++r)
              if (kl + r > qrel) s_acc[i][j][r] = -1e30f;
          }
        }

        // exp2 + per-lane row-sum + pack to bf16 pairs
        uint32_t w[4][2];
        float ls = 0.f;
        #pragma unroll
        for (int j = 0; j < 4; ++j) {
          float p0 = __ocml_native_exp2_f32(s_acc[i][j][0]);
          float p1 = __ocml_native_exp2_f32(s_acc[i][j][1]);
          float p2 = __ocml_native_exp2_f32(s_acc[i][j][2]);
          float p3 = __ocml_native_exp2_f32(s_acc[i][j][3]);
          ls += (p0 + p1) + (p2 + p3);
          w[j][0] = cvtpk(p0, p1);
          w[j][1] = cvtpk(p2, p3);
        }
        l_acc[i] += ls;

        // redistribute across quads: (A0,A1)->ks0 frag, (A2,A3)->ks1 frag
        pl16swap(w[0][0], w[1][0]);
        pl16swap(w[0][1], w[1][1]);
        pl16swap(w[2][0], w[3][0]);
        pl16swap(w[2][1], w[3][1]);
        union { uint32_t u[4]; bf16x8 v; } g0, g1;
        g0.u[0] = w[0][0]; g0.u[1] = w[0][1]; g0.u[2] = w[1][0]; g0.u[3] = w[1][1];
        g1.u[0] = w[2][0]; g1.u[1] = w[2][1]; g1.u[2] = w[3][0]; g1.u[3] = w[3][1];

        __builtin_amdgcn_s_setprio(1);
        #pragma unroll
        for (int j = 0; j < 4; ++j)
          o_acc[i][j] = __builtin_amdgcn_mfma_f32_16x16x32_bf16(g0.v, vf[0][j], o_acc[i][j], 0, 0, 0);
        #pragma unroll
        for (int j = 0; j < 4; ++j)
          o_acc[i][j] = __builtin_amdgcn_mfma_f32_16x16x32_bf16(g1.v, vf[1][j], o_acc[i][j], 0, 0, 0);
        __builtin_amdgcn_s_setprio(0);
      }
    }

    __syncthreads();          // drains prefetch (overlapped with compute above)
    cur ^= 1;
  }

  // l: reduce across quads (k-parallel), then broadcast per output row
  float lr[2][4];
  #pragma unroll
  for (int i = 0; i < 2; ++i) {
    float s = l_acc[i];
    s += __shfl_xor(s, 16, 64);
    s += __shfl_xor(s, 32, 64);
    #pragma unroll
    for (int r = 0; r < 4; ++r)
      lr[i][r] = __shfl(s, quad*4 + r, 16);
  }

  if (T <= 8) {                        // single chunk: write final output
    const int h = bh & 15, b_ = bh >> 4;
    #pragma unroll
    for (int i = 0; i < 2; ++i)
      #pragma unroll
      for (int j = 0; j < 4; ++j)
        #pragma unroll
        for (int r = 0; r < 4; ++r) {
          int sg = qg0 + 16*i + quad*4 + r;
          O[(size_t)(b_ * SEQ + sg) * DMODEL + h * DKH + j*16 + lrow]
              = f2bf(o_acc[i][j][r] / lr[i][r]);
        }
  } else {                             // partial: old 64-row strip slots
    const int pold = td;               // 2u + (wid>>1), in 8..31
    const int base = (pold < 16) ? (pold - 8) * 2
                   : (pold < 24) ? 16 + (pold - 16) * 3
                   :               40 + (pold - 24) * 4;
    const int slotp = (base + c) * 32 + bh;
    const int r64  = 32 * (wid & 1);   // row offset inside the 64-row strip
    #pragma unroll
    for (int i = 0; i < 2; ++i) {
      #pragma unroll
      for (int j = 0; j < 4; ++j) {
        ushort4 pk;
        pk.x = f2bf(o_acc[i][j][0]); pk.y = f2bf(o_acc[i][j][1]);
        pk.z = f2bf(o_acc[i][j][2]); pk.w = f2bf(o_acc[i][j][3]);
        *(ushort4*)&po[(size_t)slotp * 4096 + (j*16 + lrow) * 64 + r64 + 16*i + quad*4] = pk;
      }
      if (lrow == 0)
        #pragma unroll
        for (int r = 0; r < 4; ++r)
          pl[slotp * 64 + r64 + 16*i + quad*4 + r] = lr[i][r];
    }
  }
}

// ---------------- combine chunk-partials for strips p>=8 --------------------
__global__ __launch_bounds__(256) void combine(
    const u16* __restrict__ po, const float* __restrict__ pl, u16* __restrict__ ab) {
  __shared__ u16 Ls[64][68];
  const int b  = blockIdx.x;          // 0..767
  const int p  = 8 + (b >> 5);
  const int bh = b & 31;
  const int t  = threadIdx.x;
  const int col = t >> 2;             // 0..63
  const int r0  = (t & 3) * 16;       // 16-row slab
  const int base = (p < 16) ? (p - 8) * 2
                 : (p < 24) ? 16 + (p - 16) * 3
                 :            40 + (p - 24) * 4;
  const int nc   = (p < 16) ? 2 : (p < 24) ? 3 : 4;

  float acc[16], lsum[16];
  const size_t s0 = (size_t)(base * 32 + bh);
  const u16*   q0 = po + s0 * 4096 + col * 64 + r0;
  const float* l0 = pl + s0 * 64 + r0;
  #pragma unroll
  for (int q4 = 0; q4 < 4; ++q4) {
    ushort4 a  = *(const ushort4*)(q0 + q4 * 4);
    ushort4 c2 = *(const ushort4*)(q0 + (size_t)32 * 4096 + q4 * 4);
    acc[q4*4+0] = bf2f(a.x) + bf2f(c2.x);
    acc[q4*4+1] = bf2f(a.y) + bf2f(c2.y);
    acc[q4*4+2] = bf2f(a.z) + bf2f(c2.z);
    acc[q4*4+3] = bf2f(a.w) + bf2f(c2.w);
    float4 f = *(const float4*)(l0 + q4 * 4);
    float4 g = *(const float4*)(l0 + 32 * 64 + q4 * 4);
    lsum[q4*4+0] = f.x + g.x; lsum[q4*4+1] = f.y + g.y;
    lsum[q4*4+2] = f.z + g.z; lsum[q4*4+3] = f.w + g.w;
  }
  if (nc >= 3) {
    #pragma unroll
    for (int q4 = 0; q4 < 4; ++q4) {
      ushort4 a = *(const ushort4*)(q0 + (size_t)64 * 4096 + q4 * 4);
      acc[q4*4+0] += bf2f(a.x); acc[q4*4+1] += bf2f(a.y);
      acc[q4*4+2] += bf2f(a.z); acc[q4*4+3] += bf2f(a.w);
      float4 f = *(const float4*)(l0 + 64 * 64 + q4 * 4);
      lsum[q4*4+0] += f.x; lsum[q4*4+1] += f.y;
      lsum[q4*4+2] += f.z; lsum[q4*4+3] += f.w;
    }
  }
  if (nc == 4) {
    #pragma unroll
    for (int q4 = 0; q4 < 4; ++q4) {
      ushort4 a = *(const ushort4*)(q0 + (size_t)96 * 4096 + q4 * 4);
      acc[q4*4+0] += bf2f(a.x); acc[q4*4+1] += bf2f(a.y);
      acc[q4*4+2] += bf2f(a.z); acc[q4*4+3] += bf2f(a.w);
      float4 f = *(const float4*)(l0 + 96 * 64 + q4 * 4);
      lsum[q4*4+0] += f.x; lsum[q4*4+1] += f.y;
      lsum[q4*4+2] += f.z; lsum[q4*4+3] += f.w;
    }
  }
  #pragma unroll
  for (int q = 0; q < 16; ++q)
    Ls[r0 + q][col] = f2bf(acc[q] / lsum[q]);
  __syncthreads();

  const int row = t >> 2;
  const int c0  = (t & 3) * 16;
  const int b_ = bh >> 4, h = bh & 15;
  u16* dst = ab + (size_t)(b_ * SEQ + 64 * p + row) * DMODEL + h * DKH + c0;
  #pragma unroll
  for (int q = 0; q < 16; q += 4)
    *(ushort4*)(dst + q) = *(const ushort4*)&Ls[row][c0 + q];
}

// ---------------- launcher ---------------------------------------------------
extern "C" void kernel_launch(void* const* d_in, const int* in_sizes, int n_in,
                              void* d_out, int out_size, void* d_ws, size_t ws_size,
                              hipStream_t stream) {
  const float* x  = (const float*)d_in[0];
  const float* Wq = (const float*)d_in[1];
  const float* Wk = (const float*)d_in[2];
  const float* Wv = (const float*)d_in[3];
  const float* Wo = (const float*)d_in[4];
  float* out = (float*)d_out;

  u16* xb  = (u16*)d_ws;                               // 4M u16
  u16* wqb = xb  + (size_t)MTOT * DMODEL;              // 1M each
  u16* wkb = wqb + (size_t)DMODEL * DMODEL;
  u16* wvb = wkb + (size_t)DMODEL * DMODEL;
  u16* wob = wvb + (size_t)DMODEL * DMODEL;
  u16* qb  = wob + (size_t)DMODEL * DMODEL;            // [B,H,S,dk]
  u16* kb  = qb  + (size_t)MTOT * DMODEL;              // [B,H,S,dk]
  u16* vb  = kb  + (size_t)MTOT * DMODEL;              // [B,H,dk,VSTR]
  u16* ab  = vb  + (size_t)BATCH * NHEADS * DKH * VSTR;
  u16* po  = ab  + (size_t)MTOT * DMODEL;              // 2304 slots x 4096 u16
  float* pl = (float*)(po + (size_t)2304 * 4096);      // 2304 x 64 f32

  cvt_all<<<8192, 256, 0, stream>>>(x, Wq, Wk, Wv, Wo, xb, wqb);

  const float qscale = 0.125f * 1.44269504088896340736f;
  gemm_qkv<<<dim3(32, 16), 256, 0, stream>>>(
      xb, wqb, wkb, wvb, qb, kb, vb, qscale);

  attn<<<1280, 256, 0, stream>>>(qb, kb, vb, ab, po, pl);
  combine<<<768, 256, 0, stream>>>(po, pl, ab);

  gemm_out<<<dim3(32, 16), 256, 0, stream>>>(ab, wob, out);
}

// Round 14
// 161.477 us; speedup vs baseline: 1.0175x; 1.0074x over previous
//
#include <hip/hip_runtime.h>
#include <stdint.h>

#define BATCH  2
#define SEQ    2048
#define DMODEL 1024
#define NHEADS 16
#define DKH    64
#define MTOT   (BATCH*SEQ)   // 4096
#define VSTR   (SEQ + 32)    // padded V row stride

typedef unsigned short u16;
typedef __bf16 bf16x8 __attribute__((ext_vector_type(8)));
typedef float  f32x4  __attribute__((ext_vector_type(4)));

extern "C" __device__ float __ocml_native_exp2_f32(float);   // raw v_exp_f32

__device__ __forceinline__ u16 f2bf(float f) {
  union { float f; uint32_t u; } v; v.f = f;
  uint32_t u = v.u;
  return (u16)((u + 0x7FFFu + ((u >> 16) & 1u)) >> 16);   // RNE
}
__device__ __forceinline__ float bf2f(u16 h) {
  union { uint32_t u; float f; } v; v.u = (uint32_t)h << 16; return v.f;
}

__device__ __forceinline__ void gld_lds16(const void* g, void* l) {
  __builtin_amdgcn_global_load_lds(
      (__attribute__((address_space(1))) void*)g,
      (__attribute__((address_space(3))) void*)l, 16, 0, 0);
}

// pack two f32 -> one u32 of 2x bf16 (RNE), gfx950 has no builtin (m240)
__device__ __forceinline__ uint32_t cvtpk(float lo, float hi) {
  uint32_t r;
  asm("v_cvt_pk_bf16_f32 %0, %1, %2" : "=v"(r) : "v"(lo), "v"(hi));
  return r;
}
// gfx950 v_permlane16_swap_b32: odd 16-lane rows of a <-> even rows of b
__device__ __forceinline__ void pl16swap(uint32_t& a, uint32_t& b) {
  asm volatile("v_permlane16_swap_b32 %0, %1" : "+v"(a), "+v"(b));
}

// ---------------- fp32 -> bf16 convert, x + all 4 weights in one launch -----
__global__ void cvt_all(const float* __restrict__ x, const float* __restrict__ wa,
                        const float* __restrict__ wb, const float* __restrict__ wc,
                        const float* __restrict__ wd,
                        u16* __restrict__ xb, u16* __restrict__ wdst) {
  const int blk = blockIdx.x;
  const int tid = threadIdx.x;
  if (blk < 4096) {                    // x: 4M elements
    size_t o = (size_t)blk * 1024 + tid * 4;
    float4 f = *(const float4*)(x + o);
    ushort4 p;
    p.x = f2bf(f.x); p.y = f2bf(f.y); p.z = f2bf(f.z); p.w = f2bf(f.w);
    *(ushort4*)(xb + o) = p;
  } else {                             // weights: 4 x 1M elements, dst contiguous
    int j = blk - 4096;
    const float* ws[4] = {wa, wb, wc, wd};
    size_t src_o = (size_t)(j & 1023) * 1024 + tid * 4;
    size_t dst_o = (size_t)j * 1024 + tid * 4;
    float4 f = *(const float4*)(ws[j >> 10] + src_o);
    ushort4 p;
    p.x = f2bf(f.x); p.y = f2bf(f.y); p.z = f2bf(f.z); p.w = f2bf(f.w);
    *(ushort4*)(wdst + dst_o) = p;
  }
}

// ---------------- fused QKV GEMM: BK=128, 8 barriers, XCD n-pinning ---------
// Grid supplies only 2 blocks/CU, so 80KB LDS (A 128x128 + 3x B 64x128)
// costs nothing: BK=64->128 halves the barrier count; each vmcnt(0)+barrier
// drain is amortized over 96 MFMAs (~460cy) instead of 48 (~230cy). m132's
// BK=128 regression came from occupancy 3->2; here occupancy is grid-capped
// at 2 regardless. Swizzle: 16 chunks/row, source pre-swizzled by row&15
// (LDS dest linear, required by global_load_lds), read XORs with lrow.
__global__ __launch_bounds__(256, 2) void gemm_qkv(
    const u16* __restrict__ xb, const u16* __restrict__ wq,
    const u16* __restrict__ wk, const u16* __restrict__ wv,
    u16* __restrict__ q, u16* __restrict__ k, u16* __restrict__ v, float qscale) {
  __shared__ __align__(16) u16 lA[128 * 128];      // 32KB
  __shared__ __align__(16) u16 lB[3][64 * 128];    // 48KB

  const int tid  = threadIdx.x;
  const int lane = tid & 63;
  const int lrow = lane & 15;
  const int quad = lane >> 4;
  const int wave = tid >> 6;
  const int wm   = (wave & 1) * 64;
  const int wn   = (wave >> 1) * 32;

  // XCD-aware remap: bid = by*32+bx (dispatch order); xcd=bid&7 gets n-pair
  const int bid   = blockIdx.y * 32 + blockIdx.x;
  const int xcd   = bid & 7;
  const int slot  = bid >> 3;            // 0..63
  const int m0    = (slot >> 1) * 128;
  const int n_idx = xcd * 2 + (slot & 1);
  const int n0    = n_idx * 64;
  const u16* Ws[3] = {wq, wk, wv};

  f32x4 acc[3][4][2] = {};

  for (int k0 = 0; k0 < DMODEL; k0 += 128) {
    #pragma unroll
    for (int r = 0; r < 8; ++r) {       // A: 128 rows x 128 cols
      int off  = r * 4096 + tid * 16;
      int row  = off >> 8;
      int c16  = (off >> 4) & 15;
      int colb = (c16 ^ (row & 15)) << 4;
      gld_lds16((const char*)xb + ((size_t)(m0 + row) * DMODEL + k0) * 2 + colb,
                (char*)lA + off);
    }
    #pragma unroll
    for (int z = 0; z < 3; ++z)
      #pragma unroll
      for (int r = 0; r < 4; ++r) {     // B: 64 rows x 128 cols each
        int off  = r * 4096 + tid * 16;
        int row  = off >> 8;
        int c16  = (off >> 4) & 15;
        int colb = (c16 ^ (row & 15)) << 4;
        gld_lds16((const char*)Ws[z] + ((size_t)(n0 + row) * DMODEL + k0) * 2 + colb,
                  (char*)&lB[z][0] + off);
      }
    __syncthreads();
    #pragma unroll
    for (int ks = 0; ks < 4; ++ks) {
      const int ro = ((((ks << 2) | quad) ^ lrow) << 3);
      bf16x8 a[4], b[3][2];
      #pragma unroll
      for (int i = 0; i < 4; ++i)
        a[i] = *(const bf16x8*)(lA + (wm + i*16 + lrow) * 128 + ro);
      #pragma unroll
      for (int z = 0; z < 3; ++z)
        #pragma unroll
        for (int j = 0; j < 2; ++j)
          b[z][j] = *(const bf16x8*)(&lB[z][0] + (wn + j*16 + lrow) * 128 + ro);
      #pragma unroll
      for (int z = 0; z < 3; ++z)
        #pragma unroll
        for (int i = 0; i < 4; ++i)
          #pragma unroll
          for (int j = 0; j < 2; ++j)
            acc[z][i][j] = __builtin_amdgcn_mfma_f32_16x16x32_bf16(a[i], b[z][j], acc[z][i][j], 0, 0, 0);
    }
    __syncthreads();
  }

  const int rb = quad * 4, cb = lrow;
  const int h  = n_idx;
  u16* outs[3] = {q, k, v};
  #pragma unroll
  for (int z = 0; z < 3; ++z) {
    u16* out = outs[z];
    if (z == 2) {
      #pragma unroll
      for (int i = 0; i < 4; ++i)
        #pragma unroll
        for (int j = 0; j < 2; ++j) {
          int row0 = m0 + wm + i*16 + rb;
          int d_   = wn + j*16 + cb;
          int b_ = row0 >> 11, s0 = row0 & 2047;
          ushort4 pk;
          pk.x = f2bf(acc[z][i][j][0]); pk.y = f2bf(acc[z][i][j][1]);
          pk.z = f2bf(acc[z][i][j][2]); pk.w = f2bf(acc[z][i][j][3]);
          *(ushort4*)&out[((size_t)(b_*NHEADS + h) * DKH + d_) * VSTR + s0] = pk;
        }
    } else {
      const float scale = (z == 0) ? qscale : 1.0f;
      #pragma unroll
      for (int i = 0; i < 4; ++i)
        #pragma unroll
        for (int j = 0; j < 2; ++j)
          #pragma unroll
          for (int r = 0; r < 4; ++r) {
            int row = m0 + wm + i*16 + rb + r;
            int d_  = wn + j*16 + cb;
            int b_ = row >> 11, s_ = row & 2047;
            out[(((size_t)(b_*NHEADS + h) * SEQ + s_) << 6) + d_] =
                f2bf(acc[z][i][j][r] * scale);
          }
    }
  }
}

// ---------------- GEMM core: 128x64 block tile (for gemm_out, R10 form) -----
__device__ __forceinline__ void gemm_core64(const u16* A, const u16* W,
                                            int m0, int n0, f32x4 acc[4][2],
                                            u16* lA, u16* lB) {
  const int tid  = threadIdx.x;
  const int lane = tid & 63;
  const int lrow = lane & 15;
  const int quad = lane >> 4;
  const int wave = tid >> 6;
  const int wm   = (wave & 1) * 64;
  const int wn   = (wave >> 1) * 32;
  const int sx   = lrow & 7;

  for (int k0 = 0; k0 < DMODEL; k0 += 64) {
    #pragma unroll
    for (int r = 0; r < 4; ++r) {
      int off  = r * 4096 + tid * 16;
      int row  = off >> 7;
      int c16  = (off >> 4) & 7;
      int colb = (c16 ^ (row & 7)) << 4;
      gld_lds16((const char*)A + ((size_t)(m0 + row) * DMODEL + k0) * 2 + colb,
                (char*)lA + off);
    }
    #pragma unroll
    for (int r = 0; r < 2; ++r) {
      int off  = r * 4096 + tid * 16;
      int row  = off >> 7;
      int c16  = (off >> 4) & 7;
      int colb = (c16 ^ (row & 7)) << 4;
      gld_lds16((const char*)W + ((size_t)(n0 + row) * DMODEL + k0) * 2 + colb,
                (char*)lB + off);
    }
    __syncthreads();
    #pragma unroll
    for (int ks = 0; ks < 2; ++ks) {
      bf16x8 a[4], b[2];
      const int ro = ((((ks << 2) | quad) ^ sx) << 3);
      #pragma unroll
      for (int i = 0; i < 4; ++i)
        a[i] = *(const bf16x8*)(lA + (wm + i*16 + lrow) * 64 + ro);
      #pragma unroll
      for (int j = 0; j < 2; ++j)
        b[j] = *(const bf16x8*)(lB + (wn + j*16 + lrow) * 64 + ro);
      #pragma unroll
      for (int i = 0; i < 4; ++i)
        #pragma unroll
        for (int j = 0; j < 2; ++j)
          acc[i][j] = __builtin_amdgcn_mfma_f32_16x16x32_bf16(a[i], b[j], acc[i][j], 0, 0, 0);
    }
    __syncthreads();
  }
}

// ---------------- output projection -> fp32 (R10 form) ----------------------
__global__ __launch_bounds__(256, 3) void gemm_out(
    const u16* __restrict__ ab, const u16* __restrict__ wo, float* __restrict__ out) {
  __shared__ __align__(16) u16 lA[128 * 64];
  __shared__ __align__(16) u16 lB[64 * 64];
  const int m0 = blockIdx.x * 128, n0 = blockIdx.y * 64;
  f32x4 acc[4][2] = {};
  gemm_core64(ab, wo, m0, n0, acc, lA, lB);

  const int lane = threadIdx.x & 63;
  const int wave = threadIdx.x >> 6;
  const int wm = (wave & 1) * 64, wn = (wave >> 1) * 32;
  const int rb = (lane >> 4) * 4, cb = lane & 15;
  #pragma unroll
  for (int i = 0; i < 4; ++i)
    #pragma unroll
    for (int j = 0; j < 2; ++j)
      #pragma unroll
      for (int r = 0; r < 4; ++r)
        out[(size_t)(m0 + wm + i*16 + rb + r) * DMODEL + (n0 + wn + j*16 + cb)]
            = acc[i][j][r];
}

// ---------------- flash attention v16: v15 + XCD bh-pinning -----------------
// job entry e = u*4 + c; LPT: 28 len-8, then len-6, len-4, len-2 (4 each)
__device__ const uint8_t JT[40] = {
  60,61,62,63, 56,57,58, 52,53,54, 48,49,50, 44,45,46, 40,41, 36,37,
  32,33, 28,29, 24, 20, 16, 12,
  59,42,25,8, 55,38,21,4, 51,34,17,0
};

__device__ __forceinline__ void stage_kv(const u16* Kg, const u16* Vg, int t,
                                         u16* lK, u16* lV, int tid) {
  #pragma unroll
  for (int r = 0; r < 2; ++r) {
    int off  = r * 4096 + tid * 16;
    int row  = off >> 7;
    int colb = (((off >> 4) & 7) ^ (row & 7)) << 4;
    gld_lds16((const char*)Kg + ((size_t)(t*64 + row) * DKH) * 2 + colb,
              (char*)lK + off);
    gld_lds16((const char*)Vg + ((size_t)row * VSTR + t*64) * 2 + colb,
              (char*)lV + off);
  }
}

__global__ __launch_bounds__(256, 3) void attn(
    const u16* __restrict__ Q, const u16* __restrict__ K,
    const u16* __restrict__ V, u16* __restrict__ O,
    u16* __restrict__ po, float* __restrict__ pl) {
  __shared__ __align__(16) u16 lK[2][64 * 64];
  __shared__ __align__(16) u16 lV[2][64 * 64];

  const int tid  = threadIdx.x;
  const int wid  = tid >> 6;          // wave owns 32 q-rows: 32*wid..+31
  const int lane = tid & 63;
  const int lrow = lane & 15;
  const int quad = lane >> 4;
  const int sx   = lrow & 7;
  const int pq   = ((quad & 1) << 1) | (quad >> 1);   // pi(quad) for V frags

  // XCD-aware remap: xcd = bid&7 owns bh in {xcd, xcd+8, xcd+16, xcd+24}
  const int bid  = blockIdx.x;
  const int xcd  = bid & 7;
  const int slot = bid >> 3;          // 0..159
  const int bh   = ((slot & 3) << 3) | xcd;
  const int g    = slot >> 2;         // 0..39, monotone in bid -> LPT kept
  const int e  = JT[g];
  const int u  = e >> 2, c = e & 3;
  const int lo = c * 8;
  const int T  = 2*u + 2;
  const int hi = (lo + 8 < T) ? lo + 8 : T;
  const int td = 2*u + (wid >> 1);    // this wave's diagonal tile
  const int qg0 = 128*u + 32*wid;     // wave's first global q row

  const u16* Qg = Q + (size_t)bh * SEQ * DKH;
  const u16* Kg = K + (size_t)bh * SEQ * DKH;
  const u16* Vg = V + (size_t)bh * DKH * VSTR;

  bf16x8 aq[2][2];
  #pragma unroll
  for (int i = 0; i < 2; ++i)
    #pragma unroll
    for (int ks = 0; ks < 2; ++ks)
      aq[i][ks] = *(const bf16x8*)(Qg + (size_t)(qg0 + 16*i + lrow) * DKH + ks*32 + quad*8);

  f32x4 o_acc[2][4] = {};
  float l_acc[2] = {};

  stage_kv(Kg, Vg, lo, &lK[0][0], &lV[0][0], tid);
  __syncthreads();
  int cur = 0;

  for (int t = lo; t < hi; ++t) {
    if (t + 1 < hi)
      stage_kv(Kg, Vg, t + 1, &lK[cur ^ 1][0], &lV[cur ^ 1][0], tid);

    if (t <= td) {                     // wave-uniform: skip fully-masked tiles
      // ---- K fragments, then QK^T for both i-subtiles ---------------------
      f32x4 s_acc[2][4] = {};
      {
        bf16x8 kf[2][4];
        #pragma unroll
        for (int ks = 0; ks < 2; ++ks) {
          const int kro = ((((ks << 2) | quad) ^ sx) << 3);
          #pragma unroll
          for (int j = 0; j < 4; ++j)
            kf[ks][j] = *(const bf16x8*)(&lK[cur][0] + (j*16 + lrow) * 64 + kro);
        }
        __builtin_amdgcn_s_setprio(1);
        #pragma unroll
        for (int i = 0; i < 2; ++i)
          #pragma unroll
          for (int ks = 0; ks < 2; ++ks)
            #pragma unroll
            for (int j = 0; j < 4; ++j)
              s_acc[i][j] = __builtin_amdgcn_mfma_f32_16x16x32_bf16(kf[ks][j], aq[i][ks], s_acc[i][j], 0, 0, 0);
        __builtin_amdgcn_s_setprio(0);
      }

      // ---- V fragments (kf dead; ds_read latency hides under softmax) -----
      bf16x8 vf[2][4];
      #pragma unroll
      for (int ks = 0; ks < 2; ++ks) {
        const int vro = ((((ks << 2) | pq) ^ sx) << 3);
        #pragma unroll
        for (int j = 0; j < 4; ++j)
          vf[ks][j] = *(const bf16x8*)(&lV[cur][0] + (j*16 + lrow) * 64 + vro);
      }

      #pragma unroll
      for (int i = 0; i < 2; ++i) {
        if (t >= td) {
          const int qrel = qg0 + 16*i + lrow - 64*t;
          #pragma unroll
          for (int j = 0; j < 4; ++j) {
            int kl = j*16 + quad*4;
            #pragma unroll
            for (int r = 0; r < 4; ++r)
              if (kl + r > qrel) s_acc[i][j][r] = -1e30f;
          }
        }

        // exp2 + per-lane row-sum + pack to bf16 pairs
        uint32_t w[4][2];
        float ls = 0.f;
        #pragma unroll
        for (int j = 0; j < 4; ++j) {
          float p0 = __ocml_native_exp2_f32(s_acc[i][j][0]);
          float p1 = __ocml_native_exp2_f32(s_acc[i][j][1]);
          float p2 = __ocml_native_exp2_f32(s_acc[i][j][2]);
          float p3 = __ocml_native_exp2_f32(s_acc[i][j][3]);
          ls += (p0 + p1) + (p2 + p3);
          w[j][0] = cvtpk(p0, p1);
          w[j][1] = cvtpk(p2, p3);
        }
        l_acc[i] += ls;

        // redistribute across quads: (A0,A1)->ks0 frag, (A2,A3)->ks1 frag
        pl16swap(w[0][0], w[1][0]);
        pl16swap(w[0][1], w[1][1]);
        pl16swap(w[2][0], w[3][0]);
        pl16swap(w[2][1], w[3][1]);
        union { uint32_t u[4]; bf16x8 v; } g0, g1;
        g0.u[0] = w[0][0]; g0.u[1] = w[0][1]; g0.u[2] = w[1][0]; g0.u[3] = w[1][1];
        g1.u[0] = w[2][0]; g1.u[1] = w[2][1]; g1.u[2] = w[3][0]; g1.u[3] = w[3][1];

        __builtin_amdgcn_s_setprio(1);
        #pragma unroll
        for (int j = 0; j < 4; ++j)
          o_acc[i][j] = __builtin_amdgcn_mfma_f32_16x16x32_bf16(g0.v, vf[0][j], o_acc[i][j], 0, 0, 0);
        #pragma unroll
        for (int j = 0; j < 4; ++j)
          o_acc[i][j] = __builtin_amdgcn_mfma_f32_16x16x32_bf16(g1.v, vf[1][j], o_acc[i][j], 0, 0, 0);
        __builtin_amdgcn_s_setprio(0);
      }
    }

    __syncthreads();          // drains prefetch (overlapped with compute above)
    cur ^= 1;
  }

  // l: reduce across quads (k-parallel), then broadcast per output row
  float lr[2][4];
  #pragma unroll
  for (int i = 0; i < 2; ++i) {
    float s = l_acc[i];
    s += __shfl_xor(s, 16, 64);
    s += __shfl_xor(s, 32, 64);
    #pragma unroll
    for (int r = 0; r < 4; ++r)
      lr[i][r] = __shfl(s, quad*4 + r, 16);
  }

  if (T <= 8) {                        // single chunk: write final output
    const int h = bh & 15, b_ = bh >> 4;
    #pragma unroll
    for (int i = 0; i < 2; ++i)
      #pragma unroll
      for (int j = 0; j < 4; ++j)
        #pragma unroll
        for (int r = 0; r < 4; ++r) {
          int sg = qg0 + 16*i + quad*4 + r;
          O[(size_t)(b_ * SEQ + sg) * DMODEL + h * DKH + j*16 + lrow]
              = f2bf(o_acc[i][j][r] / lr[i][r]);
        }
  } else {                             // partial: old 64-row strip slots
    const int pold = td;               // 2u + (wid>>1), in 8..31
    const int base = (pold < 16) ? (pold - 8) * 2
                   : (pold < 24) ? 16 + (pold - 16) * 3
                   :               40 + (pold - 24) * 4;
    const int slotp = (base + c) * 32 + bh;
    const int r64  = 32 * (wid & 1);   // row offset inside the 64-row strip
    #pragma unroll
    for (int i = 0; i < 2; ++i) {
      #pragma unroll
      for (int j = 0; j < 4; ++j) {
        ushort4 pk;
        pk.x = f2bf(o_acc[i][j][0]); pk.y = f2bf(o_acc[i][j][1]);
        pk.z = f2bf(o_acc[i][j][2]); pk.w = f2bf(o_acc[i][j][3]);
        *(ushort4*)&po[(size_t)slotp * 4096 + (j*16 + lrow) * 64 + r64 + 16*i + quad*4] = pk;
      }
      if (lrow == 0)
        #pragma unroll
        for (int r = 0; r < 4; ++r)
          pl[slotp * 64 + r64 + 16*i + quad*4 + r] = lr[i][r];
    }
  }
}

// ---------------- combine chunk-partials for strips p>=8 --------------------
__global__ __launch_bounds__(256) void combine(
    const u16* __restrict__ po, const float* __restrict__ pl, u16* __restrict__ ab) {
  __shared__ u16 Ls[64][68];
  const int b  = blockIdx.x;          // 0..767
  const int p  = 8 + (b >> 5);
  const int bh = b & 31;
  const int t  = threadIdx.x;
  const int col = t >> 2;             // 0..63
  const int r0  = (t & 3) * 16;       // 16-row slab
  const int base = (p < 16) ? (p - 8) * 2
                 : (p < 24) ? 16 + (p - 16) * 3
                 :            40 + (p - 24) * 4;
  const int nc   = (p < 16) ? 2 : (p < 24) ? 3 : 4;

  float acc[16], lsum[16];
  const size_t s0 = (size_t)(base * 32 + bh);
  const u16*   q0 = po + s0 * 4096 + col * 64 + r0;
  const float* l0 = pl + s0 * 64 + r0;
  #pragma unroll
  for (int q4 = 0; q4 < 4; ++q4) {
    ushort4 a  = *(const ushort4*)(q0 + q4 * 4);
    ushort4 c2 = *(const ushort4*)(q0 + (size_t)32 * 4096 + q4 * 4);
    acc[q4*4+0] = bf2f(a.x) + bf2f(c2.x);
    acc[q4*4+1] = bf2f(a.y) + bf2f(c2.y);
    acc[q4*4+2] = bf2f(a.z) + bf2f(c2.z);
    acc[q4*4+3] = bf2f(a.w) + bf2f(c2.w);
    float4 f = *(const float4*)(l0 + q4 * 4);
    float4 g = *(const float4*)(l0 + 32 * 64 + q4 * 4);
    lsum[q4*4+0] = f.x + g.x; lsum[q4*4+1] = f.y + g.y;
    lsum[q4*4+2] = f.z + g.z; lsum[q4*4+3] = f.w + g.w;
  }
  if (nc >= 3) {
    #pragma unroll
    for (int q4 = 0; q4 < 4; ++q4) {
      ushort4 a = *(const ushort4*)(q0 + (size_t)64 * 4096 + q4 * 4);
      acc[q4*4+0] += bf2f(a.x); acc[q4*4+1] += bf2f(a.y);
      acc[q4*4+2] += bf2f(a.z); acc[q4*4+3] += bf2f(a.w);
      float4 f = *(const float4*)(l0 + 64 * 64 + q4 * 4);
      lsum[q4*4+0] += f.x; lsum[q4*4+1] += f.y;
      lsum[q4*4+2] += f.z; lsum[q4*4+3] += f.w;
    }
  }
  if (nc == 4) {
    #pragma unroll
    for (int q4 = 0; q4 < 4; ++q4) {
      ushort4 a = *(const ushort4*)(q0 + (size_t)96 * 4096 + q4 * 4);
      acc[q4*4+0] += bf2f(a.x); acc[q4*4+1] += bf2f(a.y);
      acc[q4*4+2] += bf2f(a.z); acc[q4*4+3] += bf2f(a.w);
      float4 f = *(const float4*)(l0 + 96 * 64 + q4 * 4);
      lsum[q4*4+0] += f.x; lsum[q4*4+1] += f.y;
      lsum[q4*4+2] += f.z; lsum[q4*4+3] += f.w;
    }
  }
  #pragma unroll
  for (int q = 0; q < 16; ++q)
    Ls[r0 + q][col] = f2bf(acc[q] / lsum[q]);
  __syncthreads();

  const int row = t >> 2;
  const int c0  = (t & 3) * 16;
  const int b_ = bh >> 4, h = bh & 15;
  u16* dst = ab + (size_t)(b_ * SEQ + 64 * p + row) * DMODEL + h * DKH + c0;
  #pragma unroll
  for (int q = 0; q < 16; q += 4)
    *(ushort4*)(dst + q) = *(const ushort4*)&Ls[row][c0 + q];
}

// ---------------- launcher ---------------------------------------------------
extern "C" void kernel_launch(void* const* d_in, const int* in_sizes, int n_in,
                              void* d_out, int out_size, void* d_ws, size_t ws_size,
                              hipStream_t stream) {
  const float* x  = (const float*)d_in[0];
  const float* Wq = (const float*)d_in[1];
  const float* Wk = (const float*)d_in[2];
  const float* Wv = (const float*)d_in[3];
  const float* Wo = (const float*)d_in[4];
  float* out = (float*)d_out;

  u16* xb  = (u16*)d_ws;                               // 4M u16
  u16* wqb = xb  + (size_t)MTOT * DMODEL;              // 1M each
  u16* wkb = wqb + (size_t)DMODEL * DMODEL;
  u16* wvb = wkb + (size_t)DMODEL * DMODEL;
  u16* wob = wvb + (size_t)DMODEL * DMODEL;
  u16* qb  = wob + (size_t)DMODEL * DMODEL;            // [B,H,S,dk]
  u16* kb  = qb  + (size_t)MTOT * DMODEL;              // [B,H,S,dk]
  u16* vb  = kb  + (size_t)MTOT * DMODEL;              // [B,H,dk,VSTR]
  u16* ab  = vb  + (size_t)BATCH * NHEADS * DKH * VSTR;
  u16* po  = ab  + (size_t)MTOT * DMODEL;              // 2304 slots x 4096 u16
  float* pl = (float*)(po + (size_t)2304 * 4096);      // 2304 x 64 f32

  cvt_all<<<8192, 256, 0, stream>>>(x, Wq, Wk, Wv, Wo, xb, wqb);

  const float qscale = 0.125f * 1.44269504088896340736f;
  gemm_qkv<<<dim3(32, 16), 256, 0, stream>>>(
      xb, wqb, wkb, wvb, qb, kb, vb, qscale);

  attn<<<1280, 256, 0, stream>>>(qb, kb, vb, ab, po, pl);
  combine<<<768, 256, 0, stream>>>(po, pl, ab);

  gemm_out<<<dim3(32, 16), 256, 0, stream>>>(ab, wob, out);
}

// Round 15
// 160.354 us; speedup vs baseline: 1.0247x; 1.0070x over previous
//
#include <hip/hip_runtime.h>
#include <stdint.h>

#define BATCH  2
#define SEQ    2048
#define DMODEL 1024
#define NHEADS 16
#define DKH    64
#define MTOT   (BATCH*SEQ)   // 4096
#define VSTR   (SEQ + 32)    // padded V row stride

typedef unsigned short u16;
typedef __bf16 bf16x8 __attribute__((ext_vector_type(8)));
typedef float  f32x4  __attribute__((ext_vector_type(4)));

extern "C" __device__ float __ocml_native_exp2_f32(float);   // raw v_exp_f32

__device__ __forceinline__ u16 f2bf(float f) {
  union { float f; uint32_t u; } v; v.f = f;
  uint32_t u = v.u;
  return (u16)((u + 0x7FFFu + ((u >> 16) & 1u)) >> 16);   // RNE
}
__device__ __forceinline__ float bf2f(u16 h) {
  union { uint32_t u; float f; } v; v.u = (uint32_t)h << 16; return v.f;
}

__device__ __forceinline__ void gld_lds16(const void* g, void* l) {
  __builtin_amdgcn_global_load_lds(
      (__attribute__((address_space(1))) void*)g,
      (__attribute__((address_space(3))) void*)l, 16, 0, 0);
}

// pack two f32 -> one u32 of 2x bf16 (RNE), gfx950 has no builtin (m240)
__device__ __forceinline__ uint32_t cvtpk(float lo, float hi) {
  uint32_t r;
  asm("v_cvt_pk_bf16_f32 %0, %1, %2" : "=v"(r) : "v"(lo), "v"(hi));
  return r;
}
// gfx950 v_permlane16_swap_b32: odd 16-lane rows of a <-> even rows of b
__device__ __forceinline__ void pl16swap(uint32_t& a, uint32_t& b) {
  asm volatile("v_permlane16_swap_b32 %0, %1" : "+v"(a), "+v"(b));
}

// ---------------- fp32 -> bf16 convert, x + all 4 weights in one launch -----
__global__ void cvt_all(const float* __restrict__ x, const float* __restrict__ wa,
                        const float* __restrict__ wb, const float* __restrict__ wc,
                        const float* __restrict__ wd,
                        u16* __restrict__ xb, u16* __restrict__ wdst) {
  const int blk = blockIdx.x;
  const int tid = threadIdx.x;
  if (blk < 4096) {                    // x: 4M elements
    size_t o = (size_t)blk * 1024 + tid * 4;
    float4 f = *(const float4*)(x + o);
    ushort4 p;
    p.x = f2bf(f.x); p.y = f2bf(f.y); p.z = f2bf(f.z); p.w = f2bf(f.w);
    *(ushort4*)(xb + o) = p;
  } else {                             // weights: 4 x 1M elements, dst contiguous
    int j = blk - 4096;
    const float* ws[4] = {wa, wb, wc, wd};
    size_t src_o = (size_t)(j & 1023) * 1024 + tid * 4;
    size_t dst_o = (size_t)j * 1024 + tid * 4;
    float4 f = *(const float4*)(ws[j >> 10] + src_o);
    ushort4 p;
    p.x = f2bf(f.x); p.y = f2bf(f.y); p.z = f2bf(f.z); p.w = f2bf(f.w);
    *(ushort4*)(wdst + dst_o) = p;
  }
}

// ---------------- fused QKV GEMM: dbuf + COUNTED vmcnt (T4) -----------------
// __syncthreads drains vmcnt(0) including the prefetch (why R11's dbuf was
// neutral). Here: counted s_waitcnt vmcnt(10) + raw s_barrier keeps the
// prefetch in flight across the barrier; second barrier protects the buffer
// being overwritten. Grid supplies 2 blocks/CU so 80KB dbuf LDS is free.
__device__ __forceinline__ void stage_qkv(const u16* xb, const u16* w0,
                                          const u16* w1, const u16* w2,
                                          int m0, int n0, int k0, int tid,
                                          u16* lA, u16* lB0) {
  #pragma unroll
  for (int r = 0; r < 4; ++r) {       // A: 128 rows
    int off  = r * 4096 + tid * 16;
    int row  = off >> 7;
    int colb = (((off >> 4) & 7) ^ (row & 7)) << 4;
    gld_lds16((const char*)xb + ((size_t)(m0 + row) * DMODEL + k0) * 2 + colb,
              (char*)lA + off);
  }
  const u16* Ws[3] = {w0, w1, w2};
  #pragma unroll
  for (int z = 0; z < 3; ++z)
    #pragma unroll
    for (int r = 0; r < 2; ++r) {     // B: 64 rows each
      int off  = r * 4096 + tid * 16;
      int row  = off >> 7;
      int colb = (((off >> 4) & 7) ^ (row & 7)) << 4;
      gld_lds16((const char*)Ws[z] + ((size_t)(n0 + row) * DMODEL + k0) * 2 + colb,
                (char*)(lB0 + z * 4096) + off);
    }
}

__global__ __launch_bounds__(256, 2) void gemm_qkv(
    const u16* __restrict__ xb, const u16* __restrict__ wq,
    const u16* __restrict__ wk, const u16* __restrict__ wv,
    u16* __restrict__ q, u16* __restrict__ k, u16* __restrict__ v, float qscale) {
  __shared__ __align__(16) u16 lA[2][128 * 64];
  __shared__ __align__(16) u16 lB[2][3][64 * 64];

  const int tid  = threadIdx.x;
  const int lane = tid & 63;
  const int lrow = lane & 15;
  const int quad = lane >> 4;
  const int wave = tid >> 6;
  const int wm   = (wave & 1) * 64;
  const int wn   = (wave >> 1) * 32;
  const int sx   = lrow & 7;

  // XCD-aware remap (kept from R13): xcd=bid&7 gets an n-pair
  const int bid   = blockIdx.y * 32 + blockIdx.x;
  const int xcd   = bid & 7;
  const int slot  = bid >> 3;            // 0..63
  const int m0    = (slot >> 1) * 128;
  const int n_idx = xcd * 2 + (slot & 1);
  const int n0    = n_idx * 64;

  f32x4 acc[3][4][2] = {};

  stage_qkv(xb, wq, wk, wv, m0, n0, 0, tid, &lA[0][0], &lB[0][0][0]);
  int cur = 0;

  for (int k0 = 0; k0 < DMODEL; k0 += 64) {
    const bool pf = (k0 + 64 < DMODEL);
    if (pf)
      stage_qkv(xb, wq, wk, wv, m0, n0, k0 + 64, tid,
                &lA[cur ^ 1][0], &lB[cur ^ 1][0][0]);
    if (pf) asm volatile("s_waitcnt vmcnt(10)" ::: "memory");
    else    asm volatile("s_waitcnt vmcnt(0)"  ::: "memory");
    __builtin_amdgcn_s_barrier();      // current tile collectively ready
    #pragma unroll
    for (int ks = 0; ks < 2; ++ks) {
      const int ro = ((((ks << 2) | quad) ^ sx) << 3);
      bf16x8 a[4], b[3][2];
      #pragma unroll
      for (int i = 0; i < 4; ++i)
        a[i] = *(const bf16x8*)(&lA[cur][0] + (wm + i*16 + lrow) * 64 + ro);
      #pragma unroll
      for (int z = 0; z < 3; ++z)
        #pragma unroll
        for (int j = 0; j < 2; ++j)
          b[z][j] = *(const bf16x8*)(&lB[cur][z][0] + (wn + j*16 + lrow) * 64 + ro);
      #pragma unroll
      for (int z = 0; z < 3; ++z)
        #pragma unroll
        for (int i = 0; i < 4; ++i)
          #pragma unroll
          for (int j = 0; j < 2; ++j)
            acc[z][i][j] = __builtin_amdgcn_mfma_f32_16x16x32_bf16(a[i], b[z][j], acc[z][i][j], 0, 0, 0);
    }
    __builtin_amdgcn_s_barrier();      // all done reading buf before overwrite
    cur ^= 1;
  }

  const int rb = quad * 4, cb = lrow;
  const int h  = n_idx;
  u16* outs[3] = {q, k, v};
  #pragma unroll
  for (int z = 0; z < 3; ++z) {
    u16* out = outs[z];
    if (z == 2) {
      #pragma unroll
      for (int i = 0; i < 4; ++i)
        #pragma unroll
        for (int j = 0; j < 2; ++j) {
          int row0 = m0 + wm + i*16 + rb;
          int d_   = wn + j*16 + cb;
          int b_ = row0 >> 11, s0 = row0 & 2047;
          ushort4 pk;
          pk.x = f2bf(acc[z][i][j][0]); pk.y = f2bf(acc[z][i][j][1]);
          pk.z = f2bf(acc[z][i][j][2]); pk.w = f2bf(acc[z][i][j][3]);
          *(ushort4*)&out[((size_t)(b_*NHEADS + h) * DKH + d_) * VSTR + s0] = pk;
        }
    } else {
      const float scale = (z == 0) ? qscale : 1.0f;
      #pragma unroll
      for (int i = 0; i < 4; ++i)
        #pragma unroll
        for (int j = 0; j < 2; ++j)
          #pragma unroll
          for (int r = 0; r < 4; ++r) {
            int row = m0 + wm + i*16 + rb + r;
            int d_  = wn + j*16 + cb;
            int b_ = row >> 11, s_ = row & 2047;
            out[(((size_t)(b_*NHEADS + h) * SEQ + s_) << 6) + d_] =
                f2bf(acc[z][i][j][r] * scale);
          }
    }
  }
}

// ---------------- output projection: dbuf + counted vmcnt -------------------
__device__ __forceinline__ void stage_ab(const u16* A, const u16* W,
                                         int m0, int n0, int k0, int tid,
                                         u16* lA, u16* lB) {
  #pragma unroll
  for (int r = 0; r < 4; ++r) {
    int off  = r * 4096 + tid * 16;
    int row  = off >> 7;
    int colb = (((off >> 4) & 7) ^ (row & 7)) << 4;
    gld_lds16((const char*)A + ((size_t)(m0 + row) * DMODEL + k0) * 2 + colb,
              (char*)lA + off);
  }
  #pragma unroll
  for (int r = 0; r < 2; ++r) {
    int off  = r * 4096 + tid * 16;
    int row  = off >> 7;
    int colb = (((off >> 4) & 7) ^ (row & 7)) << 4;
    gld_lds16((const char*)W + ((size_t)(n0 + row) * DMODEL + k0) * 2 + colb,
              (char*)lB + off);
  }
}

__global__ __launch_bounds__(256, 3) void gemm_out(
    const u16* __restrict__ ab, const u16* __restrict__ wo, float* __restrict__ out) {
  __shared__ __align__(16) u16 lA[2][128 * 64];
  __shared__ __align__(16) u16 lB[2][64 * 64];
  const int m0 = blockIdx.x * 128, n0 = blockIdx.y * 64;

  const int tid  = threadIdx.x;
  const int lane = tid & 63;
  const int lrow = lane & 15;
  const int quad = lane >> 4;
  const int wave = tid >> 6;
  const int wm   = (wave & 1) * 64;
  const int wn   = (wave >> 1) * 32;
  const int sx   = lrow & 7;

  f32x4 acc[4][2] = {};

  stage_ab(ab, wo, m0, n0, 0, tid, &lA[0][0], &lB[0][0]);
  int cur = 0;

  for (int k0 = 0; k0 < DMODEL; k0 += 64) {
    const bool pf = (k0 + 64 < DMODEL);
    if (pf)
      stage_ab(ab, wo, m0, n0, k0 + 64, tid, &lA[cur ^ 1][0], &lB[cur ^ 1][0]);
    if (pf) asm volatile("s_waitcnt vmcnt(6)" ::: "memory");
    else    asm volatile("s_waitcnt vmcnt(0)" ::: "memory");
    __builtin_amdgcn_s_barrier();
    #pragma unroll
    for (int ks = 0; ks < 2; ++ks) {
      bf16x8 a[4], b[2];
      const int ro = ((((ks << 2) | quad) ^ sx) << 3);
      #pragma unroll
      for (int i = 0; i < 4; ++i)
        a[i] = *(const bf16x8*)(&lA[cur][0] + (wm + i*16 + lrow) * 64 + ro);
      #pragma unroll
      for (int j = 0; j < 2; ++j)
        b[j] = *(const bf16x8*)(&lB[cur][0] + (wn + j*16 + lrow) * 64 + ro);
      #pragma unroll
      for (int i = 0; i < 4; ++i)
        #pragma unroll
        for (int j = 0; j < 2; ++j)
          acc[i][j] = __builtin_amdgcn_mfma_f32_16x16x32_bf16(a[i], b[j], acc[i][j], 0, 0, 0);
    }
    __builtin_amdgcn_s_barrier();
    cur ^= 1;
  }

  const int rb = (lane >> 4) * 4, cb = lane & 15;
  #pragma unroll
  for (int i = 0; i < 4; ++i)
    #pragma unroll
    for (int j = 0; j < 2; ++j)
      #pragma unroll
      for (int r = 0; r < 4; ++r)
        out[(size_t)(m0 + wm + i*16 + rb + r) * DMODEL + (n0 + wn + j*16 + cb)]
            = acc[i][j][r];
}

// ---------------- flash attention v17: v16 + counted-vmcnt pipeline ---------
// job entry e = u*4 + c; LPT: 28 len-8, then len-6, len-4, len-2 (4 each)
__device__ const uint8_t JT[40] = {
  60,61,62,63, 56,57,58, 52,53,54, 48,49,50, 44,45,46, 40,41, 36,37,
  32,33, 28,29, 24, 20, 16, 12,
  59,42,25,8, 55,38,21,4, 51,34,17,0
};

__device__ __forceinline__ void stage_kv(const u16* Kg, const u16* Vg, int t,
                                         u16* lK, u16* lV, int tid) {
  #pragma unroll
  for (int r = 0; r < 2; ++r) {
    int off  = r * 4096 + tid * 16;
    int row  = off >> 7;
    int colb = (((off >> 4) & 7) ^ (row & 7)) << 4;
    gld_lds16((const char*)Kg + ((size_t)(t*64 + row) * DKH) * 2 + colb,
              (char*)lK + off);
    gld_lds16((const char*)Vg + ((size_t)row * VSTR + t*64) * 2 + colb,
              (char*)lV + off);
  }
}

__global__ __launch_bounds__(256, 3) void attn(
    const u16* __restrict__ Q, const u16* __restrict__ K,
    const u16* __restrict__ V, u16* __restrict__ O,
    u16* __restrict__ po, float* __restrict__ pl) {
  __shared__ __align__(16) u16 lK[2][64 * 64];
  __shared__ __align__(16) u16 lV[2][64 * 64];

  const int tid  = threadIdx.x;
  const int wid  = tid >> 6;          // wave owns 32 q-rows: 32*wid..+31
  const int lane = tid & 63;
  const int lrow = lane & 15;
  const int quad = lane >> 4;
  const int sx   = lrow & 7;
  const int pq   = ((quad & 1) << 1) | (quad >> 1);   // pi(quad) for V frags

  // XCD-aware remap: xcd = bid&7 owns bh in {xcd, xcd+8, xcd+16, xcd+24}
  const int bid  = blockIdx.x;
  const int xcd  = bid & 7;
  const int slot = bid >> 3;          // 0..159
  const int bh   = ((slot & 3) << 3) | xcd;
  const int g    = slot >> 2;         // 0..39, monotone in bid -> LPT kept
  const int e  = JT[g];
  const int u  = e >> 2, c = e & 3;
  const int lo = c * 8;
  const int T  = 2*u + 2;
  const int hi = (lo + 8 < T) ? lo + 8 : T;
  const int td = 2*u + (wid >> 1);    // this wave's diagonal tile
  const int qg0 = 128*u + 32*wid;     // wave's first global q row

  const u16* Qg = Q + (size_t)bh * SEQ * DKH;
  const u16* Kg = K + (size_t)bh * SEQ * DKH;
  const u16* Vg = V + (size_t)bh * DKH * VSTR;

  bf16x8 aq[2][2];
  #pragma unroll
  for (int i = 0; i < 2; ++i)
    #pragma unroll
    for (int ks = 0; ks < 2; ++ks)
      aq[i][ks] = *(const bf16x8*)(Qg + (size_t)(qg0 + 16*i + lrow) * DKH + ks*32 + quad*8);

  f32x4 o_acc[2][4] = {};
  float l_acc[2] = {};

  stage_kv(Kg, Vg, lo, &lK[0][0], &lV[0][0], tid);
  int cur = 0;

  for (int t = lo; t < hi; ++t) {
    const bool pf = (t + 1 < hi);
    if (pf)
      stage_kv(Kg, Vg, t + 1, &lK[cur ^ 1][0], &lV[cur ^ 1][0], tid);
    // counted vmcnt: aq global loads are long retired; only stage loads count
    if (pf) asm volatile("s_waitcnt vmcnt(4)" ::: "memory");
    else    asm volatile("s_waitcnt vmcnt(0)" ::: "memory");
    __builtin_amdgcn_s_barrier();      // tile t collectively in LDS

    if (t <= td) {                     // wave-uniform: skip fully-masked tiles
      // ---- K fragments, then QK^T for both i-subtiles ---------------------
      f32x4 s_acc[2][4] = {};
      {
        bf16x8 kf[2][4];
        #pragma unroll
        for (int ks = 0; ks < 2; ++ks) {
          const int kro = ((((ks << 2) | quad) ^ sx) << 3);
          #pragma unroll
          for (int j = 0; j < 4; ++j)
            kf[ks][j] = *(const bf16x8*)(&lK[cur][0] + (j*16 + lrow) * 64 + kro);
        }
        __builtin_amdgcn_s_setprio(1);
        #pragma unroll
        for (int i = 0; i < 2; ++i)
          #pragma unroll
          for (int ks = 0; ks < 2; ++ks)
            #pragma unroll
            for (int j = 0; j < 4; ++j)
              s_acc[i][j] = __builtin_amdgcn_mfma_f32_16x16x32_bf16(kf[ks][j], aq[i][ks], s_acc[i][j], 0, 0, 0);
        __builtin_amdgcn_s_setprio(0);
      }

      // ---- V fragments (kf dead; ds_read latency hides under softmax) -----
      bf16x8 vf[2][4];
      #pragma unroll
      for (int ks = 0; ks < 2; ++ks) {
        const int vro = ((((ks << 2) | pq) ^ sx) << 3);
        #pragma unroll
        for (int j = 0; j < 4; ++j)
          vf[ks][j] = *(const bf16x8*)(&lV[cur][0] + (j*16 + lrow) * 64 + vro);
      }

      #pragma unroll
      for (int i = 0; i < 2; ++i) {
        if (t >= td) {
          const int qrel = qg0 + 16*i + lrow - 64*t;
          #pragma unroll
          for (int j = 0; j < 4; ++j) {
            int kl = j*16 + quad*4;
            #pragma unroll
            for (int r = 0; r < 4; ++r)
              if (kl + r > qrel) s_acc[i][j][r] = -1e30f;
          }
        }

        // exp2 + per-lane row-sum + pack to bf16 pairs
        uint32_t w[4][2];
        float ls = 0.f;
        #pragma unroll
        for (int j = 0; j < 4; ++j) {
          float p0 = __ocml_native_exp2_f32(s_acc[i][j][0]);
          float p1 = __ocml_native_exp2_f32(s_acc[i][j][1]);
          float p2 = __ocml_native_exp2_f32(s_acc[i][j][2]);
          float p3 = __ocml_native_exp2_f32(s_acc[i][j][3]);
          ls += (p0 + p1) + (p2 + p3);
          w[j][0] = cvtpk(p0, p1);
          w[j][1] = cvtpk(p2, p3);
        }
        l_acc[i] += ls;

        // redistribute across quads: (A0,A1)->ks0 frag, (A2,A3)->ks1 frag
        pl16swap(w[0][0], w[1][0]);
        pl16swap(w[0][1], w[1][1]);
        pl16swap(w[2][0], w[3][0]);
        pl16swap(w[2][1], w[3][1]);
        union { uint32_t u[4]; bf16x8 v; } g0, g1;
        g0.u[0] = w[0][0]; g0.u[1] = w[0][1]; g0.u[2] = w[1][0]; g0.u[3] = w[1][1];
        g1.u[0] = w[2][0]; g1.u[1] = w[2][1]; g1.u[2] = w[3][0]; g1.u[3] = w[3][1];

        __builtin_amdgcn_s_setprio(1);
        #pragma unroll
        for (int j = 0; j < 4; ++j)
          o_acc[i][j] = __builtin_amdgcn_mfma_f32_16x16x32_bf16(g0.v, vf[0][j], o_acc[i][j], 0, 0, 0);
        #pragma unroll
        for (int j = 0; j < 4; ++j)
          o_acc[i][j] = __builtin_amdgcn_mfma_f32_16x16x32_bf16(g1.v, vf[1][j], o_acc[i][j], 0, 0, 0);
        __builtin_amdgcn_s_setprio(0);
      }
    }

    __builtin_amdgcn_s_barrier();      // all done reading cur before overwrite
    cur ^= 1;
  }

  // l: reduce across quads (k-parallel), then broadcast per output row
  float lr[2][4];
  #pragma unroll
  for (int i = 0; i < 2; ++i) {
    float s = l_acc[i];
    s += __shfl_xor(s, 16, 64);
    s += __shfl_xor(s, 32, 64);
    #pragma unroll
    for (int r = 0; r < 4; ++r)
      lr[i][r] = __shfl(s, quad*4 + r, 16);
  }

  if (T <= 8) {                        // single chunk: write final output
    const int h = bh & 15, b_ = bh >> 4;
    #pragma unroll
    for (int i = 0; i < 2; ++i)
      #pragma unroll
      for (int j = 0; j < 4; ++j)
        #pragma unroll
        for (int r = 0; r < 4; ++r) {
          int sg = qg0 + 16*i + quad*4 + r;
          O[(size_t)(b_ * SEQ + sg) * DMODEL + h * DKH + j*16 + lrow]
              = f2bf(o_acc[i][j][r] / lr[i][r]);
        }
  } else {                             // partial: old 64-row strip slots
    const int pold = td;               // 2u + (wid>>1), in 8..31
    const int base = (pold < 16) ? (pold - 8) * 2
                   : (pold < 24) ? 16 + (pold - 16) * 3
                   :               40 + (pold - 24) * 4;
    const int slotp = (base + c) * 32 + bh;
    const int r64  = 32 * (wid & 1);   // row offset inside the 64-row strip
    #pragma unroll
    for (int i = 0; i < 2; ++i) {
      #pragma unroll
      for (int j = 0; j < 4; ++j) {
        ushort4 pk;
        pk.x = f2bf(o_acc[i][j][0]); pk.y = f2bf(o_acc[i][j][1]);
        pk.z = f2bf(o_acc[i][j][2]); pk.w = f2bf(o_acc[i][j][3]);
        *(ushort4*)&po[(size_t)slotp * 4096 + (j*16 + lrow) * 64 + r64 + 16*i + quad*4] = pk;
      }
      if (lrow == 0)
        #pragma unroll
        for (int r = 0; r < 4; ++r)
          pl[slotp * 64 + r64 + 16*i + quad*4 + r] = lr[i][r];
    }
  }
}

// ---------------- combine chunk-partials for strips p>=8 --------------------
__global__ __launch_bounds__(256) void combine(
    const u16* __restrict__ po, const float* __restrict__ pl, u16* __restrict__ ab) {
  __shared__ u16 Ls[64][68];
  const int b  = blockIdx.x;          // 0..767
  const int p  = 8 + (b >> 5);
  const int bh = b & 31;
  const int t  = threadIdx.x;
  const int col = t >> 2;             // 0..63
  const int r0  = (t & 3) * 16;       // 16-row slab
  const int base = (p < 16) ? (p - 8) * 2
                 : (p < 24) ? 16 + (p - 16) * 3
                 :            40 + (p - 24) * 4;
  const int nc   = (p < 16) ? 2 : (p < 24) ? 3 : 4;

  float acc[16], lsum[16];
  const size_t s0 = (size_t)(base * 32 + bh);
  const u16*   q0 = po + s0 * 4096 + col * 64 + r0;
  const float* l0 = pl + s0 * 64 + r0;
  #pragma unroll
  for (int q4 = 0; q4 < 4; ++q4) {
    ushort4 a  = *(const ushort4*)(q0 + q4 * 4);
    ushort4 c2 = *(const ushort4*)(q0 + (size_t)32 * 4096 + q4 * 4);
    acc[q4*4+0] = bf2f(a.x) + bf2f(c2.x);
    acc[q4*4+1] = bf2f(a.y) + bf2f(c2.y);
    acc[q4*4+2] = bf2f(a.z) + bf2f(c2.z);
    acc[q4*4+3] = bf2f(a.w) + bf2f(c2.w);
    float4 f = *(const float4*)(l0 + q4 * 4);
    float4 g = *(const float4*)(l0 + 32 * 64 + q4 * 4);
    lsum[q4*4+0] = f.x + g.x; lsum[q4*4+1] = f.y + g.y;
    lsum[q4*4+2] = f.z + g.z; lsum[q4*4+3] = f.w + g.w;
  }
  if (nc >= 3) {
    #pragma unroll
    for (int q4 = 0; q4 < 4; ++q4) {
      ushort4 a = *(const ushort4*)(q0 + (size_t)64 * 4096 + q4 * 4);
      acc[q4*4+0] += bf2f(a.x); acc[q4*4+1] += bf2f(a.y);
      acc[q4*4+2] += bf2f(a.z); acc[q4*4+3] += bf2f(a.w);
      float4 f = *(const float4*)(l0 + 64 * 64 + q4 * 4);
      lsum[q4*4+0] += f.x; lsum[q4*4+1] += f.y;
      lsum[q4*4+2] += f.z; lsum[q4*4+3] += f.w;
    }
  }
  if (nc == 4) {
    #pragma unroll
    for (int q4 = 0; q4 < 4; ++q4) {
      ushort4 a = *(const ushort4*)(q0 + (size_t)96 * 4096 + q4 * 4);
      acc[q4*4+0] += bf2f(a.x); acc[q4*4+1] += bf2f(a.y);
      acc[q4*4+2] += bf2f(a.z); acc[q4*4+3] += bf2f(a.w);
      float4 f = *(const float4*)(l0 + 96 * 64 + q4 * 4);
      lsum[q4*4+0] += f.x; lsum[q4*4+1] += f.y;
      lsum[q4*4+2] += f.z; lsum[q4*4+3] += f.w;
    }
  }
  #pragma unroll
  for (int q = 0; q < 16; ++q)
    Ls[r0 + q][col] = f2bf(acc[q] / lsum[q]);
  __syncthreads();

  const int row = t >> 2;
  const int c0  = (t & 3) * 16;
  const int b_ = bh >> 4, h = bh & 15;
  u16* dst = ab + (size_t)(b_ * SEQ + 64 * p + row) * DMODEL + h * DKH + c0;
  #pragma unroll
  for (int q = 0; q < 16; q += 4)
    *(ushort4*)(dst + q) = *(const ushort4*)&Ls[row][c0 + q];
}

// ---------------- launcher ---------------------------------------------------
extern "C" void kernel_launch(void* const* d_in, const int* in_sizes, int n_in,
                              void* d_out, int out_size, void* d_ws, size_t ws_size,
                              hipStream_t stream) {
  const float* x  = (const float*)d_in[0];
  const float* Wq = (const float*)d_in[1];
  const float* Wk = (const float*)d_in[2];
  const float* Wv = (const float*)d_in[3];
  const float* Wo = (const float*)d_in[4];
  float* out = (float*)d_out;

  u16* xb  = (u16*)d_ws;                               // 4M u16
  u16* wqb = xb  + (size_t)MTOT * DMODEL;              // 1M each
  u16* wkb = wqb + (size_t)DMODEL * DMODEL;
  u16* wvb = wkb + (size_t)DMODEL * DMODEL;
  u16* wob = wvb + (size_t)DMODEL * DMODEL;
  u16* qb  = wob + (size_t)DMODEL * DMODEL;            // [B,H,S,dk]
  u16* kb  = qb  + (size_t)MTOT * DMODEL;              // [B,H,S,dk]
  u16* vb  = kb  + (size_t)MTOT * DMODEL;              // [B,H,dk,VSTR]
  u16* ab  = vb  + (size_t)BATCH * NHEADS * DKH * VSTR;
  u16* po  = ab  + (size_t)MTOT * DMODEL;              // 2304 slots x 4096 u16
  float* pl = (float*)(po + (size_t)2304 * 4096);      // 2304 x 64 f32

  cvt_all<<<8192, 256, 0, stream>>>(x, Wq, Wk, Wv, Wo, xb, wqb);

  const float qscale = 0.125f * 1.44269504088896340736f;
  gemm_qkv<<<dim3(32, 16), 256, 0, stream>>>(
      xb, wqb, wkb, wvb, qb, kb, vb, qscale);

  attn<<<1280, 256, 0, stream>>>(qb, kb, vb, ab, po, pl);
  combine<<<768, 256, 0, stream>>>(po, pl, ab);

  gemm_out<<<dim3(32, 16), 256, 0, stream>>>(ab, wob, out);
}